// Round 2
// baseline (250.798 us; speedup 1.0000x reference)
//
#include <hip/hip_runtime.h>

#define NS   64      // state dim
#define CH   128     // channels
#define LSEQ 4096    // sequence length
#define NB   16      // batch
#define SCH  64      // chunk size
#define MCH  64      // number of chunks (LSEQ/SCH)

// workspace float offsets (total 12352 floats = 48.3 KB; X0 lives in d_out)
#define WS_ABAR 0          // 64*64 A_bar
#define WS_AS   4096       // 64*64 A_bar^64
#define WS_VS   8192       // 64*64 vs[j*64+i] = (A_bar^j B_bar)[i]
#define WS_BBAR 12288      // 64

// X0 stash: state entering chunk m of batch b is parked in d_out at
// out[(b*CH + 0)*LSEQ + m*SCH + i], i<64 — a region written (later) only by
// k_main block (m,b), which is also the only reader. k_bound->k_main kernel
// boundary orders the accesses.
#define X0_IDX(b, m) (((size_t)(b) * CH) * LSEQ + (size_t)(m) * SCH)

// ---------------------------------------------------------------------------
// K1: setup — A_bar, B_bar, vs[0..63], A_S = A_bar^64. Single block.
// T1 = I - 0.5dt*A is lower triangular (HiPPO) -> forward substitution.
// ---------------------------------------------------------------------------
__global__ __launch_bounds__(256) void k_setup(const float* __restrict__ A,
                                               const float* __restrict__ Bv,
                                               const float* __restrict__ dtp,
                                               float* __restrict__ ws) {
    __shared__ __align__(16) float M0[NS * 65];   // T1, later ping/pong
    __shared__ __align__(16) float M1[NS * 65];   // T2 -> A_bar, later ping/pong
    __shared__ __align__(16) float vsL[NS * 65];  // vs[j*65+i]
    __shared__ __align__(16) float Bb[NS];
    const int tid = threadIdx.x;
    const float dt = dtp[0];
    const float hdt = 0.5f * dt;

    for (int o = tid; o < NS * NS; o += 256) {
        int i = o >> 6, k = o & 63;
        float a = A[o];
        float d = (i == k) ? 1.0f : 0.0f;
        M0[i * 65 + k] = d - hdt * a;   // T1
        M1[i * 65 + k] = d + hdt * a;   // T2
    }
    __syncthreads();

    // forward substitution: column j of A_bar solved in place in M1.
    if (tid < NS) {
        int j = tid;
        for (int i = 0; i < NS; ++i) {
            float s = M1[i * 65 + j];
            for (int k = 0; k < i; ++k) s -= M0[i * 65 + k] * M1[k * 65 + j];
            M1[i * 65 + j] = s / M0[i * 65 + i];
        }
    } else if (tid == NS) {
        // B_bar = dt * inv(T1) * B
        for (int i = 0; i < NS; ++i) {
            float s = dt * Bv[i];
            for (int k = 0; k < i; ++k) s -= M0[i * 65 + k] * Bb[k];
            Bb[i] = s / M0[i * 65 + i];
        }
    }
    __syncthreads();

    // save A_bar / B_bar, seed vs[0]
    for (int o = tid; o < NS * NS; o += 256) {
        int r = o >> 6, c = o & 63;
        ws[WS_ABAR + o] = M1[r * 65 + c];
    }
    if (tid < NS) {
        ws[WS_BBAR + tid] = Bb[tid];
        vsL[tid] = Bb[tid];   // vs[0][i]
    }
    __syncthreads();

    // log-doubling: vs[j+m] = A^m vs[j]; square A^m -> A^2m (ping-pong M1<->M0)
    float* cur = M1;
    float* nxt = M0;
    for (int m = 1; m < SCH; m <<= 1) {
        for (int o = tid; o < m * NS; o += 256) {
            int j = o >> 6, i = o & 63;
            float s = 0.f;
            for (int k = 0; k < NS; ++k) s += cur[i * 65 + k] * vsL[j * 65 + k];
            vsL[(j + m) * 65 + i] = s;
        }
        __syncthreads();
        for (int o = tid; o < NS * NS; o += 256) {
            int i = o >> 6, jj = o & 63;
            float s = 0.f;
            for (int k = 0; k < NS; ++k) s += cur[i * 65 + k] * cur[k * 65 + jj];
            nxt[i * 65 + jj] = s;
        }
        __syncthreads();
        float* t = cur; cur = nxt; nxt = t;
    }
    // cur == A_bar^64
    for (int o = tid; o < NS * NS; o += 256) {
        int r = o >> 6, c = o & 63;
        ws[WS_AS + o] = cur[r * 65 + c];
        ws[WS_VS + o] = vsL[r * 65 + c];   // r=j, c=i
    }
}

// ---------------------------------------------------------------------------
// K2: per-batch chunk-boundary states. xle[m] = sum_j vs[j]*u[m*64+63-j],
// then 64-step scan x_end[m] = A_S x_end[m-1] + xle[m]; stash x_end[m-1]
// (the state ENTERING chunk m) into d_out at X0_IDX(b,m).
// One barrier per scan step (double-buffered partials; xn identical across
// waves so the redundant xcS writes are benign-by-identical-bits).
// ---------------------------------------------------------------------------
__global__ __launch_bounds__(256) void k_bound(const float* __restrict__ u,
                                               const float* __restrict__ ws,
                                               float* __restrict__ out) {
    __shared__ __align__(16) float vsS[NS * NS];    // [j*64+i]
    __shared__ __align__(16) float uB[LSEQ];        // this batch's u row
    __shared__ __align__(16) float xleS[MCH * NS];  // [m*64+i]
    __shared__ __align__(16) float xcS[NS];
    __shared__ __align__(16) float part[2][4 * NS];
    const int b = blockIdx.x, tid = threadIdx.x;
    const int i = tid & 63, q = tid >> 6;

    for (int o = tid; o < NS * NS; o += 256) vsS[o] = ws[WS_VS + o];
    for (int o = tid; o < LSEQ; o += 256) uB[o] = u[b * LSEQ + o];

    // A_S row chunk in registers: lane i, wave q holds A_S[i][16q..16q+16)
    float arow[16];
#pragma unroll
    for (int kk = 0; kk < 16; ++kk) arow[kk] = ws[WS_AS + i * NS + 16 * q + kk];
    __syncthreads();

    for (int o = tid; o < MCH * NS; o += 256) {
        int m = o >> 6, ii = o & 63;
        float s = 0.f;
        const float* ub = uB + m * SCH;
        for (int j = 0; j < SCH; ++j) s += vsS[j * 64 + ii] * ub[63 - j];
        xleS[o] = s;
    }
    if (tid < NS) xcS[tid] = 0.f;
    __syncthreads();

    for (int m = 0; m < MCH; ++m) {
        if (q == 0) out[X0_IDX(b, m) + i] = xcS[i];   // state entering chunk m
        float4 t0 = *(const float4*)(xcS + 16 * q + 0);
        float4 t1 = *(const float4*)(xcS + 16 * q + 4);
        float4 t2 = *(const float4*)(xcS + 16 * q + 8);
        float4 t3 = *(const float4*)(xcS + 16 * q + 12);
        float s = arow[0] * t0.x + arow[1] * t0.y + arow[2] * t0.z + arow[3] * t0.w
                + arow[4] * t1.x + arow[5] * t1.y + arow[6] * t1.z + arow[7] * t1.w
                + arow[8] * t2.x + arow[9] * t2.y + arow[10] * t2.z + arow[11] * t2.w
                + arow[12] * t3.x + arow[13] * t3.y + arow[14] * t3.z + arow[15] * t3.w;
        part[m & 1][q * 64 + i] = s;
        __syncthreads();
        float xn = part[m & 1][i] + part[m & 1][64 + i] + part[m & 1][128 + i]
                 + part[m & 1][192 + i] + xleS[m * 64 + i];
        xcS[i] = xn;   // all waves write identical bits
    }
}

// ---------------------------------------------------------------------------
// K3: main. Block = (chunk m, batch b). Phase 1: 64-step recurrence from
// the X0 stash into LDS X[i][t]. Phase 2: Y = C @ X + D*u, C staged in
// halves into the (dead) A_bar LDS region. Coalesced float4 stores.
// ---------------------------------------------------------------------------
__global__ __launch_bounds__(256) void k_main(const float* __restrict__ u,
                                              const float* __restrict__ Cm,
                                              const float* __restrict__ Dv,
                                              const float* __restrict__ ws,
                                              float* __restrict__ out) {
    __shared__ __align__(16) float R0[NS * 65];   // A_bar, then C halves
    __shared__ __align__(16) float Xl[NS * 68];   // [i*68 + t]
    __shared__ __align__(16) float BbS[NS];
    __shared__ __align__(16) float uS[SCH];
    __shared__ __align__(16) float DS[CH];
    __shared__ __align__(16) float xcS[NS];
    __shared__ __align__(16) float part[2][4 * NS];
    const int m = blockIdx.x, b = blockIdx.y;
    const int tid = threadIdx.x;
    const int i = tid & 63, q = tid >> 6;

    for (int o = tid; o < NS * NS; o += 256) {
        int r = o >> 6, c = o & 63;
        R0[r * 65 + c] = ws[WS_ABAR + o];
    }
    if (tid < NS) {
        BbS[tid] = ws[WS_BBAR + tid];
        uS[tid]  = u[b * LSEQ + m * SCH + tid];
        xcS[tid] = out[X0_IDX(b, m) + tid];   // read stash before overwriting
    }
    if (tid < CH) DS[tid] = Dv[tid];
    __syncthreads();

    float arow[16];
#pragma unroll
    for (int kk = 0; kk < 16; ++kk) arow[kk] = R0[i * 65 + 16 * q + kk];

    for (int t = 0; t < SCH; ++t) {
        float4 t0 = *(const float4*)(xcS + 16 * q + 0);
        float4 t1 = *(const float4*)(xcS + 16 * q + 4);
        float4 t2 = *(const float4*)(xcS + 16 * q + 8);
        float4 t3 = *(const float4*)(xcS + 16 * q + 12);
        float s = arow[0] * t0.x + arow[1] * t0.y + arow[2] * t0.z + arow[3] * t0.w
                + arow[4] * t1.x + arow[5] * t1.y + arow[6] * t1.z + arow[7] * t1.w
                + arow[8] * t2.x + arow[9] * t2.y + arow[10] * t2.z + arow[11] * t2.w
                + arow[12] * t3.x + arow[13] * t3.y + arow[14] * t3.z + arow[15] * t3.w;
        part[t & 1][q * 64 + i] = s;
        __syncthreads();
        float xn = part[t & 1][i] + part[t & 1][64 + i] + part[t & 1][128 + i]
                 + part[t & 1][192 + i] + BbS[i] * uS[t];
        xcS[i] = xn;                 // all waves, identical bits
        if (q == 0) Xl[i * 68 + t] = xn;
    }
    __syncthreads();

    // phase 2: Y = C @ X  (+ D*u)
    const int tq = tid & 7, c0 = tid >> 3;
    const int t0i = 8 * tq;
    float acc[4][8];
#pragma unroll
    for (int r = 0; r < 4; ++r)
#pragma unroll
        for (int tt = 0; tt < 8; ++tt) acc[r][tt] = 0.f;

    for (int half = 0; half < 2; ++half) {
        for (int o = tid; o < NS * NS; o += 256) {
            int cc = o >> 6, ii = o & 63;
            R0[cc * 65 + ii] = Cm[(half * NS + cc) * NS + ii];
        }
        __syncthreads();
        for (int ii = 0; ii < NS; ++ii) {
            float4 xa = *(const float4*)(Xl + ii * 68 + t0i);
            float4 xb = *(const float4*)(Xl + ii * 68 + t0i + 4);
#pragma unroll
            for (int rr = 0; rr < 2; ++rr) {
                float cv = R0[(c0 + 32 * rr) * 65 + ii];
                float* a = acc[half * 2 + rr];
                a[0] += cv * xa.x; a[1] += cv * xa.y; a[2] += cv * xa.z; a[3] += cv * xa.w;
                a[4] += cv * xb.x; a[5] += cv * xb.y; a[6] += cv * xb.z; a[7] += cv * xb.w;
            }
        }
        __syncthreads();
    }

    const size_t obase = ((size_t)b * CH) * LSEQ + (size_t)m * SCH + t0i;
#pragma unroll
    for (int r = 0; r < 4; ++r) {
        int c = c0 + 32 * r;
        float dv = DS[c];
        float4 o1, o2;
        o1.x = acc[r][0] + dv * uS[t0i + 0];
        o1.y = acc[r][1] + dv * uS[t0i + 1];
        o1.z = acc[r][2] + dv * uS[t0i + 2];
        o1.w = acc[r][3] + dv * uS[t0i + 3];
        o2.x = acc[r][4] + dv * uS[t0i + 4];
        o2.y = acc[r][5] + dv * uS[t0i + 5];
        o2.z = acc[r][6] + dv * uS[t0i + 6];
        o2.w = acc[r][7] + dv * uS[t0i + 7];
        float* op = out + obase + (size_t)c * LSEQ;
        *(float4*)(op)     = o1;
        *(float4*)(op + 4) = o2;
    }
}

extern "C" void kernel_launch(void* const* d_in, const int* in_sizes, int n_in,
                              void* d_out, int out_size, void* d_ws, size_t ws_size,
                              hipStream_t stream) {
    const float* u   = (const float*)d_in[0];
    const float* A   = (const float*)d_in[1];
    const float* Bv  = (const float*)d_in[2];
    const float* Cm  = (const float*)d_in[3];
    const float* Dv  = (const float*)d_in[4];
    const float* dtp = (const float*)d_in[5];
    float* ws  = (float*)d_ws;
    float* out = (float*)d_out;

    k_setup<<<1, 256, 0, stream>>>(A, Bv, dtp, ws);
    k_bound<<<NB, 256, 0, stream>>>(u, ws, out);
    k_main<<<dim3(MCH, NB), 256, 0, stream>>>(u, Cm, Dv, ws, out);
}

// Round 3
// 197.536 us; speedup vs baseline: 1.2696x; 1.2696x over previous
//
#include <hip/hip_runtime.h>

#define NS   64      // state dim
#define CH   128     // channels
#define LSEQ 4096    // sequence length
#define NB   16      // batch
#define SCH  64      // chunk size
#define MCH  64      // number of chunks (LSEQ/SCH)
#define ST   68      // padded LDS row stride (68*4B = 16B-aligned, 2-way bank alias = free)

// workspace float offsets (total 12352 floats = 48.3 KB; X0 lives in d_out)
#define WS_ABAR 0          // 64*64 A_bar
#define WS_AS   4096       // 64*64 A_bar^64
#define WS_VS   8192       // 64*64 vs[j*64+i] = (A_bar^j B_bar)[i]
#define WS_BBAR 12288      // 64

// X0 stash: state entering chunk m of batch b parked in d_out (see R1 notes):
// slot is written later only by k_main block (m,b), which is the only reader.
#define X0_IDX(b, m) (((size_t)(b) * CH) * LSEQ + (size_t)(m) * SCH)

// ---------------------------------------------------------------------------
// K1: setup — A_bar, B_bar, vs[0..63], A_S = A_bar^64. Single block.
// All heavy GEMM work uses M + M^T copies in LDS so reads are ds_read_b128,
// and exploits A_bar lower-triangularity (upper tiles skipped, stay zero).
// ---------------------------------------------------------------------------
__global__ __launch_bounds__(256) void k_setup(const float* __restrict__ A,
                                               const float* __restrict__ Bv,
                                               const float* __restrict__ dtp,
                                               float* __restrict__ ws) {
    __shared__ __align__(16) float M [NS * ST];   // T2 -> A_bar -> ping/pong
    __shared__ __align__(16) float Mt[NS * ST];   // transpose of M
    __shared__ __align__(16) float N [NS * ST];   // T1 -> ping/pong
    __shared__ __align__(16) float Nt[NS * ST];
    __shared__ __align__(16) float VT[NS * ST];   // VT[k][j] = vs[j][k]
    __shared__ float Bb[NS], rdiag[NS];
    const int tid = threadIdx.x;
    const float dt = dtp[0];
    const float hdt = 0.5f * dt;

    // zero everything once; upper-triangle zeros persist through all levels
    for (int o = tid; o < NS * ST; o += 256) { M[o] = 0.f; Mt[o] = 0.f; N[o] = 0.f; Nt[o] = 0.f; }
    __syncthreads();

    // T1 = I - hdt*A -> N ; T2 = I + hdt*A -> M. A is lower-triangular (HiPPO),
    // upper entries of input are exactly 0 so upper stays 0.
    for (int o = tid; o < NS * NS; o += 256) {
        int i = o >> 6, k = o & 63;
        float a = A[o];
        float d = (i == k) ? 1.0f : 0.0f;
        N[i * ST + k] = d - hdt * a;
        M[i * ST + k] = d + hdt * a;
    }
    __syncthreads();
    if (tid < NS) rdiag[tid] = 1.0f / N[tid * ST + tid];
    __syncthreads();

    // forward substitution, column-parallel: thread j solves column j of
    // A_bar = inv(T1)*T2 in place in M; thread 64 solves B_bar.
    if (tid < NS) {
        const int j = tid;
        for (int i = 0; i < NS; ++i) {
            float s = M[i * ST + j];
            float s0 = 0.f, s1 = 0.f, s2 = 0.f, s3 = 0.f;
            int k = 0;
            for (; k + 4 <= i; k += 4) {
                float4 nv = *(const float4*)&N[i * ST + k];
                s0 -= nv.x * M[(k + 0) * ST + j];
                s1 -= nv.y * M[(k + 1) * ST + j];
                s2 -= nv.z * M[(k + 2) * ST + j];
                s3 -= nv.w * M[(k + 3) * ST + j];
            }
            for (; k < i; ++k) s0 -= N[i * ST + k] * M[k * ST + j];
            M[i * ST + j] = (s + ((s0 + s1) + (s2 + s3))) * rdiag[i];
        }
    } else if (tid == NS) {
        for (int i = 0; i < NS; ++i) {
            float s = dt * Bv[i];
            for (int k = 0; k < i; ++k) s -= N[i * ST + k] * Bb[k];
            Bb[i] = s * rdiag[i];
        }
    }
    __syncthreads();

    // save A_bar/B_bar, build Mt, seed VT col 0
    for (int o = tid; o < NS * NS; o += 256) {
        int i = o >> 6, k = o & 63;
        float v = M[i * ST + k];
        ws[WS_ABAR + o] = v;
        Mt[k * ST + i] = v;
    }
    if (tid < NS) { ws[WS_BBAR + tid] = Bb[tid]; VT[tid * ST + 0] = Bb[tid]; }
    __syncthreads();

    // doubling: at loop head cm = A^m (lower-tri), VT cols [0,m) valid.
    // expand VT cols [m,2m), square cm -> nm = A^(2m). One barrier per level.
    float *cm = M, *cmt = Mt, *nm = N, *nmt = Nt;
    for (int m = 1; m < SCH; m <<= 1) {
        // --- vs expansion: VT[i][j+m] = sum_{k<=i} A^m[i][k] * VT[k][j], j<m
        if (m <= 2) {
            if (tid < NS * m) {
                int i = tid & 63, j = tid >> 6;
                float s = 0.f;
                for (int k = 0; k <= i; ++k) s += cmt[k * ST + i] * VT[k * ST + j];
                VT[i * ST + (j + m)] = s;
            }
        } else {
            const int jt_cnt = m >> 2;                 // 1,2,4,8
            if (tid < 16 * jt_cnt) {
                const int sh = __ffs(jt_cnt) - 1;
                const int it = tid >> sh, jt = tid & (jt_cnt - 1);
                const int i0 = it * 4, j0 = jt * 4;
                float4 a0 = {0,0,0,0}, a1 = {0,0,0,0}, a2 = {0,0,0,0}, a3 = {0,0,0,0};
                for (int k = 0; k < i0 + 4; ++k) {     // Mt[k][i]=0 for i<k handles interior
                    float4 av = *(const float4*)&cmt[k * ST + i0];  // A^m[i0..i0+3][k]
                    float4 bv = *(const float4*)&VT[k * ST + j0];   // vs[j0..j0+3][k]
                    a0.x += av.x * bv.x; a0.y += av.x * bv.y; a0.z += av.x * bv.z; a0.w += av.x * bv.w;
                    a1.x += av.y * bv.x; a1.y += av.y * bv.y; a1.z += av.y * bv.z; a1.w += av.y * bv.w;
                    a2.x += av.z * bv.x; a2.y += av.z * bv.y; a2.z += av.z * bv.z; a2.w += av.z * bv.w;
                    a3.x += av.w * bv.x; a3.y += av.w * bv.y; a3.z += av.w * bv.z; a3.w += av.w * bv.w;
                }
                *(float4*)&VT[(i0 + 0) * ST + (j0 + m)] = a0;
                *(float4*)&VT[(i0 + 1) * ST + (j0 + m)] = a1;
                *(float4*)&VT[(i0 + 2) * ST + (j0 + m)] = a2;
                *(float4*)&VT[(i0 + 3) * ST + (j0 + m)] = a3;
            }
        }
        // --- squaring (lower tiles only): nm = cm*cm, nmt = transpose
        {
            const int it = tid >> 4, jt = tid & 15;
            const int i0 = it * 4, j0 = jt * 4;
            if (j0 <= i0) {
                float4 a0 = {0,0,0,0}, a1 = {0,0,0,0}, a2 = {0,0,0,0}, a3 = {0,0,0,0};
                for (int k = j0; k < i0 + 4; ++k) {    // outside [j0, i0+3] terms are 0
                    float4 av = *(const float4*)&cmt[k * ST + i0];  // A[i0..i0+3][k]
                    float4 bv = *(const float4*)&cm [k * ST + j0];  // A[k][j0..j0+3]
                    a0.x += av.x * bv.x; a0.y += av.x * bv.y; a0.z += av.x * bv.z; a0.w += av.x * bv.w;
                    a1.x += av.y * bv.x; a1.y += av.y * bv.y; a1.z += av.y * bv.z; a1.w += av.y * bv.w;
                    a2.x += av.z * bv.x; a2.y += av.z * bv.y; a2.z += av.z * bv.z; a2.w += av.z * bv.w;
                    a3.x += av.w * bv.x; a3.y += av.w * bv.y; a3.z += av.w * bv.z; a3.w += av.w * bv.w;
                }
                *(float4*)&nm[(i0 + 0) * ST + j0] = a0;
                *(float4*)&nm[(i0 + 1) * ST + j0] = a1;
                *(float4*)&nm[(i0 + 2) * ST + j0] = a2;
                *(float4*)&nm[(i0 + 3) * ST + j0] = a3;
                float4 t0 = {a0.x, a1.x, a2.x, a3.x};
                float4 t1 = {a0.y, a1.y, a2.y, a3.y};
                float4 t2 = {a0.z, a1.z, a2.z, a3.z};
                float4 t3 = {a0.w, a1.w, a2.w, a3.w};
                *(float4*)&nmt[(j0 + 0) * ST + i0] = t0;
                *(float4*)&nmt[(j0 + 1) * ST + i0] = t1;
                *(float4*)&nmt[(j0 + 2) * ST + i0] = t2;
                *(float4*)&nmt[(j0 + 3) * ST + i0] = t3;
            }
        }
        __syncthreads();
        float* t;
        t = cm; cm = nm; nm = t;
        t = cmt; cmt = nmt; nmt = t;
    }

    // cm == A^64; VT complete
    for (int o = tid; o < NS * NS; o += 256) {
        int i = o >> 6, k = o & 63;
        ws[WS_AS + o] = cm[i * ST + k];
    }
    for (int o = tid; o < NS * NS; o += 256) {
        int j = o >> 6, i = o & 63;
        ws[WS_VS + o] = VT[i * ST + j];
    }
}

// ---------------------------------------------------------------------------
// K2: per-batch chunk-boundary states (unchanged this round).
// ---------------------------------------------------------------------------
__global__ __launch_bounds__(256) void k_bound(const float* __restrict__ u,
                                               const float* __restrict__ ws,
                                               float* __restrict__ out) {
    __shared__ __align__(16) float vsS[NS * NS];    // [j*64+i]
    __shared__ __align__(16) float uB[LSEQ];        // this batch's u row
    __shared__ __align__(16) float xleS[MCH * NS];  // [m*64+i]
    __shared__ __align__(16) float xcS[NS];
    __shared__ __align__(16) float part[2][4 * NS];
    const int b = blockIdx.x, tid = threadIdx.x;
    const int i = tid & 63, q = tid >> 6;

    for (int o = tid; o < NS * NS; o += 256) vsS[o] = ws[WS_VS + o];
    for (int o = tid; o < LSEQ; o += 256) uB[o] = u[b * LSEQ + o];

    float arow[16];
#pragma unroll
    for (int kk = 0; kk < 16; ++kk) arow[kk] = ws[WS_AS + i * NS + 16 * q + kk];
    __syncthreads();

    for (int o = tid; o < MCH * NS; o += 256) {
        int m = o >> 6, ii = o & 63;
        float s = 0.f;
        const float* ub = uB + m * SCH;
        for (int j = 0; j < SCH; ++j) s += vsS[j * 64 + ii] * ub[63 - j];
        xleS[o] = s;
    }
    if (tid < NS) xcS[tid] = 0.f;
    __syncthreads();

    for (int m = 0; m < MCH; ++m) {
        if (q == 0) out[X0_IDX(b, m) + i] = xcS[i];   // state entering chunk m
        float4 t0 = *(const float4*)(xcS + 16 * q + 0);
        float4 t1 = *(const float4*)(xcS + 16 * q + 4);
        float4 t2 = *(const float4*)(xcS + 16 * q + 8);
        float4 t3 = *(const float4*)(xcS + 16 * q + 12);
        float s = arow[0] * t0.x + arow[1] * t0.y + arow[2] * t0.z + arow[3] * t0.w
                + arow[4] * t1.x + arow[5] * t1.y + arow[6] * t1.z + arow[7] * t1.w
                + arow[8] * t2.x + arow[9] * t2.y + arow[10] * t2.z + arow[11] * t2.w
                + arow[12] * t3.x + arow[13] * t3.y + arow[14] * t3.z + arow[15] * t3.w;
        part[m & 1][q * 64 + i] = s;
        __syncthreads();
        float xn = part[m & 1][i] + part[m & 1][64 + i] + part[m & 1][128 + i]
                 + part[m & 1][192 + i] + xleS[m * 64 + i];
        xcS[i] = xn;   // all waves write identical bits
    }
}

// ---------------------------------------------------------------------------
// K3: main (unchanged this round).
// ---------------------------------------------------------------------------
__global__ __launch_bounds__(256) void k_main(const float* __restrict__ u,
                                              const float* __restrict__ Cm,
                                              const float* __restrict__ Dv,
                                              const float* __restrict__ ws,
                                              float* __restrict__ out) {
    __shared__ __align__(16) float R0[NS * 65];   // A_bar, then C halves
    __shared__ __align__(16) float Xl[NS * 68];   // [i*68 + t]
    __shared__ __align__(16) float BbS[NS];
    __shared__ __align__(16) float uS[SCH];
    __shared__ __align__(16) float DS[CH];
    __shared__ __align__(16) float xcS[NS];
    __shared__ __align__(16) float part[2][4 * NS];
    const int m = blockIdx.x, b = blockIdx.y;
    const int tid = threadIdx.x;
    const int i = tid & 63, q = tid >> 6;

    for (int o = tid; o < NS * NS; o += 256) {
        int r = o >> 6, c = o & 63;
        R0[r * 65 + c] = ws[WS_ABAR + o];
    }
    if (tid < NS) {
        BbS[tid] = ws[WS_BBAR + tid];
        uS[tid]  = u[b * LSEQ + m * SCH + tid];
        xcS[tid] = out[X0_IDX(b, m) + tid];   // read stash before overwriting
    }
    if (tid < CH) DS[tid] = Dv[tid];
    __syncthreads();

    float arow[16];
#pragma unroll
    for (int kk = 0; kk < 16; ++kk) arow[kk] = R0[i * 65 + 16 * q + kk];

    for (int t = 0; t < SCH; ++t) {
        float4 t0 = *(const float4*)(xcS + 16 * q + 0);
        float4 t1 = *(const float4*)(xcS + 16 * q + 4);
        float4 t2 = *(const float4*)(xcS + 16 * q + 8);
        float4 t3 = *(const float4*)(xcS + 16 * q + 12);
        float s = arow[0] * t0.x + arow[1] * t0.y + arow[2] * t0.z + arow[3] * t0.w
                + arow[4] * t1.x + arow[5] * t1.y + arow[6] * t1.z + arow[7] * t1.w
                + arow[8] * t2.x + arow[9] * t2.y + arow[10] * t2.z + arow[11] * t2.w
                + arow[12] * t3.x + arow[13] * t3.y + arow[14] * t3.z + arow[15] * t3.w;
        part[t & 1][q * 64 + i] = s;
        __syncthreads();
        float xn = part[t & 1][i] + part[t & 1][64 + i] + part[t & 1][128 + i]
                 + part[t & 1][192 + i] + BbS[i] * uS[t];
        xcS[i] = xn;                 // all waves, identical bits
        if (q == 0) Xl[i * 68 + t] = xn;
    }
    __syncthreads();

    // phase 2: Y = C @ X  (+ D*u)
    const int tq = tid & 7, c0 = tid >> 3;
    const int t0i = 8 * tq;
    float acc[4][8];
#pragma unroll
    for (int r = 0; r < 4; ++r)
#pragma unroll
        for (int tt = 0; tt < 8; ++tt) acc[r][tt] = 0.f;

    for (int half = 0; half < 2; ++half) {
        for (int o = tid; o < NS * NS; o += 256) {
            int cc = o >> 6, ii = o & 63;
            R0[cc * 65 + ii] = Cm[(half * NS + cc) * NS + ii];
        }
        __syncthreads();
        for (int ii = 0; ii < NS; ++ii) {
            float4 xa = *(const float4*)(Xl + ii * 68 + t0i);
            float4 xb = *(const float4*)(Xl + ii * 68 + t0i + 4);
#pragma unroll
            for (int rr = 0; rr < 2; ++rr) {
                float cv = R0[(c0 + 32 * rr) * 65 + ii];
                float* a = acc[half * 2 + rr];
                a[0] += cv * xa.x; a[1] += cv * xa.y; a[2] += cv * xa.z; a[3] += cv * xa.w;
                a[4] += cv * xb.x; a[5] += cv * xb.y; a[6] += cv * xb.z; a[7] += cv * xb.w;
            }
        }
        __syncthreads();
    }

    const size_t obase = ((size_t)b * CH) * LSEQ + (size_t)m * SCH + t0i;
#pragma unroll
    for (int r = 0; r < 4; ++r) {
        int c = c0 + 32 * r;
        float dv = DS[c];
        float4 o1, o2;
        o1.x = acc[r][0] + dv * uS[t0i + 0];
        o1.y = acc[r][1] + dv * uS[t0i + 1];
        o1.z = acc[r][2] + dv * uS[t0i + 2];
        o1.w = acc[r][3] + dv * uS[t0i + 3];
        o2.x = acc[r][4] + dv * uS[t0i + 4];
        o2.y = acc[r][5] + dv * uS[t0i + 5];
        o2.z = acc[r][6] + dv * uS[t0i + 6];
        o2.w = acc[r][7] + dv * uS[t0i + 7];
        float* op = out + obase + (size_t)c * LSEQ;
        *(float4*)(op)     = o1;
        *(float4*)(op + 4) = o2;
    }
}

extern "C" void kernel_launch(void* const* d_in, const int* in_sizes, int n_in,
                              void* d_out, int out_size, void* d_ws, size_t ws_size,
                              hipStream_t stream) {
    const float* u   = (const float*)d_in[0];
    const float* A   = (const float*)d_in[1];
    const float* Bv  = (const float*)d_in[2];
    const float* Cm  = (const float*)d_in[3];
    const float* Dv  = (const float*)d_in[4];
    const float* dtp = (const float*)d_in[5];
    float* ws  = (float*)d_ws;
    float* out = (float*)d_out;

    k_setup<<<1, 256, 0, stream>>>(A, Bv, dtp, ws);
    k_bound<<<NB, 256, 0, stream>>>(u, ws, out);
    k_main<<<dim3(MCH, NB), 256, 0, stream>>>(u, Cm, Dv, ws, out);
}

// Round 4
// 192.282 us; speedup vs baseline: 1.3043x; 1.0273x over previous
//
#include <hip/hip_runtime.h>

#define NS   64      // state dim
#define CH   128     // channels
#define LSEQ 4096    // sequence length
#define NB   16      // batch
#define SCH  64      // chunk size
#define MCH  64      // number of chunks (LSEQ/SCH)
#define ST   68      // padded LDS row stride (68*4 = 272 = 17*16 -> b128-aligned)
#define CT_ST 132    // C^T LDS stride (132*4 = 528 = 33*16 -> b128-aligned)

// workspace float offsets; A16 optional (guarded by ws_size at launch)
#define WS_ABAR 0          // 64*64 A_bar
#define WS_AS   4096       // 64*64 A_bar^64
#define WS_VS   8192       // 64*64 vs[j*64+i] = (A_bar^j B_bar)[i]
#define WS_BBAR 12288      // 64
#define WS_A16  12352      // 64*64 A_bar^16 (only if ws_size allows)

// X0 stash in d_out: slot (b,m) is later written only by k_main block (m,b),
// which is also its only reader; kernel boundary orders accesses.
#define X0_IDX(b, m) (((size_t)(b) * CH) * LSEQ + (size_t)(m) * SCH)

#define FMA44(av, bv)                                                          \
    a0.x += av.x * bv.x; a0.y += av.x * bv.y; a0.z += av.x * bv.z; a0.w += av.x * bv.w; \
    a1.x += av.y * bv.x; a1.y += av.y * bv.y; a1.z += av.y * bv.z; a1.w += av.y * bv.w; \
    a2.x += av.z * bv.x; a2.y += av.z * bv.y; a2.z += av.z * bv.z; a2.w += av.z * bv.w; \
    a3.x += av.w * bv.x; a3.y += av.w * bv.y; a3.z += av.w * bv.z; a3.w += av.w * bv.w;

// ---------------------------------------------------------------------------
// K1: setup — A_bar, B_bar, vs[0..63], A^16 (optional), A^64. Single block.
// Substitution kept from R3 (proven). Doubling: wave-uniform k-ranges,
// unroll-4, all ds_read_b128, one barrier per level.
// ---------------------------------------------------------------------------
__global__ __launch_bounds__(256) void k_setup(const float* __restrict__ A,
                                               const float* __restrict__ Bv,
                                               const float* __restrict__ dtp,
                                               float* __restrict__ ws,
                                               int has_a16) {
    __shared__ __align__(16) float M [NS * ST];
    __shared__ __align__(16) float Mt[NS * ST];
    __shared__ __align__(16) float N [NS * ST];
    __shared__ __align__(16) float Nt[NS * ST];
    __shared__ __align__(16) float VT[NS * ST];   // VT[k][j] = vs[j][k]
    __shared__ float Bb[NS], rdiag[NS];
    const int tid = threadIdx.x;
    const float dt = dtp[0];
    const float hdt = 0.5f * dt;

    for (int o = tid; o < NS * ST; o += 256) { M[o] = 0.f; Mt[o] = 0.f; N[o] = 0.f; Nt[o] = 0.f; }
    __syncthreads();

    for (int o = tid; o < NS * NS; o += 256) {
        int i = o >> 6, k = o & 63;
        float a = A[o];
        float d = (i == k) ? 1.0f : 0.0f;
        N[i * ST + k] = d - hdt * a;   // T1
        M[i * ST + k] = d + hdt * a;   // T2
    }
    __syncthreads();
    if (tid < NS) rdiag[tid] = 1.0f / N[tid * ST + tid];
    __syncthreads();

    // forward substitution (proven in R3): column j of A_bar in place in M
    if (tid < NS) {
        const int j = tid;
        for (int i = 0; i < NS; ++i) {
            float s = M[i * ST + j];
            float s0 = 0.f, s1 = 0.f, s2 = 0.f, s3 = 0.f;
            int k = 0;
            for (; k + 4 <= i; k += 4) {
                float4 nv = *(const float4*)&N[i * ST + k];
                s0 -= nv.x * M[(k + 0) * ST + j];
                s1 -= nv.y * M[(k + 1) * ST + j];
                s2 -= nv.z * M[(k + 2) * ST + j];
                s3 -= nv.w * M[(k + 3) * ST + j];
            }
            for (; k < i; ++k) s0 -= N[i * ST + k] * M[k * ST + j];
            M[i * ST + j] = (s + ((s0 + s1) + (s2 + s3))) * rdiag[i];
        }
    } else if (tid == NS) {
        for (int i = 0; i < NS; ++i) {
            float s = dt * Bv[i];
            for (int k = 0; k < i; ++k) s -= N[i * ST + k] * Bb[k];
            Bb[i] = s * rdiag[i];
        }
    }
    __syncthreads();

    // save A_bar/B_bar, build Mt, seed VT col 0
    for (int o = tid; o < NS * NS; o += 256) {
        int i = o >> 6, k = o & 63;
        float v = M[i * ST + k];
        ws[WS_ABAR + o] = v;
        Mt[k * ST + i] = v;
    }
    if (tid < NS) { ws[WS_BBAR + tid] = Bb[tid]; VT[tid * ST + 0] = Bb[tid]; }
    __syncthreads();

    // doubling with wave-uniform k-ranges. Wave w owns tile rows 16w..16w+15.
    float *cm = M, *cmt = Mt, *nm = N, *nmt = Nt;
    const int w4 = tid >> 6;
    const int l  = tid & 63;
    const int i0 = 16 * w4 + 4 * (l >> 4);
    const int j0 = 4 * (l & 15);
    const int kmax = 16 * (w4 + 1);     // wave-uniform; covers k <= i0+3

    for (int m = 1; m < SCH; m <<= 1) {
        // --- vs expansion: VT[:, m+j] = A^m * VT[:, j], j < m ---
        if (m == 1) {
            if (tid < NS) {
                float s = 0.f;
                for (int k = 0; k <= tid; ++k) s += cmt[k * ST + tid] * VT[k * ST];
                VT[tid * ST + 1] = s;
            }
        } else if (m == 2) {
            if (tid < 2 * NS) {
                int i = tid & 63, j = tid >> 6;
                float s = 0.f;
                for (int k = 0; k <= i; ++k) s += cmt[k * ST + i] * VT[k * ST + j];
                VT[i * ST + 2 + j] = s;
            }
        } else if (tid < 4 * m) {
            const int vi = 4 * (tid & 15), vj = 4 * (tid >> 4);
            float4 a0 = {0,0,0,0}, a1 = {0,0,0,0}, a2 = {0,0,0,0}, a3 = {0,0,0,0};
            for (int k = 0; k < NS; k += 2) {
                float4 av  = *(const float4*)&cmt[k * ST + vi];
                float4 bv  = *(const float4*)&VT [k * ST + vj];
                float4 av2 = *(const float4*)&cmt[(k + 1) * ST + vi];
                float4 bv2 = *(const float4*)&VT [(k + 1) * ST + vj];
                FMA44(av, bv)
                FMA44(av2, bv2)
            }
            *(float4*)&VT[(vi + 0) * ST + vj + m] = a0;
            *(float4*)&VT[(vi + 1) * ST + vj + m] = a1;
            *(float4*)&VT[(vi + 2) * ST + vj + m] = a2;
            *(float4*)&VT[(vi + 3) * ST + vj + m] = a3;
        }
        // --- squaring: nm = cm*cm (4x4 tiles, unroll-4, uniform k) ---
        {
            float4 a0 = {0,0,0,0}, a1 = {0,0,0,0}, a2 = {0,0,0,0}, a3 = {0,0,0,0};
            for (int k = 0; k < kmax; k += 4) {
                float4 av0 = *(const float4*)&cmt[(k + 0) * ST + i0];
                float4 bv0 = *(const float4*)&cm [(k + 0) * ST + j0];
                float4 av1 = *(const float4*)&cmt[(k + 1) * ST + i0];
                float4 bv1 = *(const float4*)&cm [(k + 1) * ST + j0];
                float4 av2 = *(const float4*)&cmt[(k + 2) * ST + i0];
                float4 bv2 = *(const float4*)&cm [(k + 2) * ST + j0];
                float4 av3 = *(const float4*)&cmt[(k + 3) * ST + i0];
                float4 bv3 = *(const float4*)&cm [(k + 3) * ST + j0];
                FMA44(av0, bv0)
                FMA44(av1, bv1)
                FMA44(av2, bv2)
                FMA44(av3, bv3)
            }
            *(float4*)&nm[(i0 + 0) * ST + j0] = a0;
            *(float4*)&nm[(i0 + 1) * ST + j0] = a1;
            *(float4*)&nm[(i0 + 2) * ST + j0] = a2;
            *(float4*)&nm[(i0 + 3) * ST + j0] = a3;
            float4 t0 = {a0.x, a1.x, a2.x, a3.x};
            float4 t1 = {a0.y, a1.y, a2.y, a3.y};
            float4 t2 = {a0.z, a1.z, a2.z, a3.z};
            float4 t3 = {a0.w, a1.w, a2.w, a3.w};
            *(float4*)&nmt[(j0 + 0) * ST + i0] = t0;
            *(float4*)&nmt[(j0 + 1) * ST + i0] = t1;
            *(float4*)&nmt[(j0 + 2) * ST + i0] = t2;
            *(float4*)&nmt[(j0 + 3) * ST + i0] = t3;
        }
        __syncthreads();
        float* t;
        t = cm; cm = nm; nm = t;
        t = cmt; cmt = nmt; nmt = t;
        if (m == 8 && has_a16) {   // cm == A^16 here
            for (int o = tid; o < NS * NS; o += 256)
                ws[WS_A16 + o] = cm[(o >> 6) * ST + (o & 63)];
        }
    }

    for (int o = tid; o < NS * NS; o += 256)
        ws[WS_AS + o] = cm[(o >> 6) * ST + (o & 63)];
    for (int o = tid; o < NS * NS; o += 256)
        ws[WS_VS + o] = VT[(o & 63) * ST + (o >> 6)];   // [j*64+i]
}

// ---------------------------------------------------------------------------
// K2: per-batch chunk-boundary states. xle via transposed-u all-b128 tiles;
// scan kept from R3 (proven).
// ---------------------------------------------------------------------------
__global__ __launch_bounds__(256) void k_bound(const float* __restrict__ u,
                                               const float* __restrict__ ws,
                                               float* __restrict__ out) {
    __shared__ __align__(16) float vsS[NS * NS];    // [j*64+i]
    __shared__ __align__(16) float uT[NS * ST];     // uT[jj][m] = u[m*64+63-jj]
    __shared__ __align__(16) float xleS[MCH * NS];  // [m*64+i]
    __shared__ __align__(16) float xcS[NS];
    __shared__ __align__(16) float part[2][4 * NS];
    const int b = blockIdx.x, tid = threadIdx.x;
    const int i = tid & 63, q = tid >> 6;

    for (int o = tid; o < NS * NS; o += 256) vsS[o] = ws[WS_VS + o];
    // stage u transposed: gather 4 coalesced scalars -> one b128 write
    {
        const int jj = tid & 63;
        for (int rep = 0; rep < 4; ++rep) {
            const int m0 = 4 * (tid >> 6) + 16 * rep;
            float4 v;
            v.x = u[b * LSEQ + (m0 + 0) * SCH + 63 - jj];
            v.y = u[b * LSEQ + (m0 + 1) * SCH + 63 - jj];
            v.z = u[b * LSEQ + (m0 + 2) * SCH + 63 - jj];
            v.w = u[b * LSEQ + (m0 + 3) * SCH + 63 - jj];
            *(float4*)&uT[jj * ST + m0] = v;
        }
    }
    float arow[16];
#pragma unroll
    for (int kk = 0; kk < 16; ++kk) arow[kk] = ws[WS_AS + i * NS + 16 * q + kk];
    __syncthreads();

    // xle[m][i] = sum_j vs[j][i] * uT[j][m]  (4x4 tiles, all b128)
    {
        const int ig = tid & 15, mg = tid >> 4;
        float4 a0 = {0,0,0,0}, a1 = {0,0,0,0}, a2 = {0,0,0,0}, a3 = {0,0,0,0};
        for (int j = 0; j < NS; j += 2) {
            float4 am  = *(const float4*)&uT [j * ST + 4 * mg];
            float4 bi  = *(const float4*)&vsS[j * NS + 4 * ig];
            float4 am2 = *(const float4*)&uT [(j + 1) * ST + 4 * mg];
            float4 bi2 = *(const float4*)&vsS[(j + 1) * NS + 4 * ig];
            FMA44(am, bi)
            FMA44(am2, bi2)
        }
        *(float4*)&xleS[(4 * mg + 0) * NS + 4 * ig] = a0;
        *(float4*)&xleS[(4 * mg + 1) * NS + 4 * ig] = a1;
        *(float4*)&xleS[(4 * mg + 2) * NS + 4 * ig] = a2;
        *(float4*)&xleS[(4 * mg + 3) * NS + 4 * ig] = a3;
    }
    if (tid < NS) xcS[tid] = 0.f;
    __syncthreads();

    for (int m = 0; m < MCH; ++m) {
        if (q == 0) out[X0_IDX(b, m) + i] = xcS[i];
        float4 t0 = *(const float4*)(xcS + 16 * q + 0);
        float4 t1 = *(const float4*)(xcS + 16 * q + 4);
        float4 t2 = *(const float4*)(xcS + 16 * q + 8);
        float4 t3 = *(const float4*)(xcS + 16 * q + 12);
        float s = arow[0] * t0.x + arow[1] * t0.y + arow[2] * t0.z + arow[3] * t0.w
                + arow[4] * t1.x + arow[5] * t1.y + arow[6] * t1.z + arow[7] * t1.w
                + arow[8] * t2.x + arow[9] * t2.y + arow[10] * t2.z + arow[11] * t2.w
                + arow[12] * t3.x + arow[13] * t3.y + arow[14] * t3.z + arow[15] * t3.w;
        part[m & 1][q * 64 + i] = s;
        __syncthreads();
        float xn = part[m & 1][i] + part[m & 1][64 + i] + part[m & 1][128 + i]
                 + part[m & 1][192 + i] + xleS[m * 64 + i];
        xcS[i] = xn;   // all waves write identical bits
    }
}

// ---------------------------------------------------------------------------
// K3 (paragraph version): phase1 = A^16 mini-scan (3 steps) + 4 independent
// 16-step recurrences, one per wave (no barriers; in-wave shuffle reduce).
// phase2 = Y = C@X via transposed-C 8cx8t tiles on 2 waves.
// ---------------------------------------------------------------------------
__global__ __launch_bounds__(256) void k_main_par(const float* __restrict__ u,
                                                  const float* __restrict__ Cm,
                                                  const float* __restrict__ Dv,
                                                  const float* __restrict__ ws,
                                                  float* __restrict__ out) {
    __shared__ __align__(16) float Xl[NS * ST];       // A_bar staging, then X[i][t]
    __shared__ __align__(16) float CtS[NS * CT_ST];   // A16 staging, then C^T
    __shared__ __align__(16) float xcW[4 * NS];       // per-wave state
    __shared__ __align__(16) float xbS[4 * NS];       // paragraph boundary states
    __shared__ __align__(16) float VSS[16 * NS];      // vs[0..15][i]
    __shared__ __align__(16) float pleS[4 * NS];
    __shared__ __align__(16) float partS[4 * NS];
    __shared__ float uS[SCH], DS[CH], bbS[NS];
    const int m = blockIdx.x, b = blockIdx.y;
    const int tid = threadIdx.x;
    const int l = tid & 63, w = tid >> 6;

    // stage A_bar -> Xl, A16 -> CtS (both b128 writes)
    for (int o = tid; o < (NS * NS) / 4; o += 256) {
        int r = o >> 4, c4 = (o & 15) * 4;
        *(float4*)&Xl[r * ST + c4]     = *(const float4*)&ws[WS_ABAR + r * NS + c4];
        *(float4*)&CtS[r * CT_ST + c4] = *(const float4*)&ws[WS_A16 + r * NS + c4];
    }
    for (int o = tid; o < 16 * NS; o += 256) VSS[o] = ws[WS_VS + o];
    if (tid < NS) {
        uS[tid]  = u[b * LSEQ + m * SCH + tid];
        bbS[tid] = ws[WS_BBAR + tid];
        xbS[tid] = out[X0_IDX(b, m) + tid];   // xb_0 = x0
    }
    if (tid < CH) DS[tid] = Dv[tid];
    __syncthreads();

    // registers: A rows for paragraph recurrence (4 rows x 16 k per lane)
    const int r0 = l & 15, q = l >> 4;
    float4 ar[4][4];
#pragma unroll
    for (int b4 = 0; b4 < 4; ++b4)
#pragma unroll
        for (int kq = 0; kq < 4; ++kq)
            ar[b4][kq] = *(const float4*)&Xl[(r0 + 16 * b4) * ST + 16 * q + 4 * kq];
    float bbr[4];
#pragma unroll
    for (int b4 = 0; b4 < 4; ++b4) bbr[b4] = bbS[r0 + 16 * b4];
    // A16 row for mini-scan (lane = row l, wave = k-chunk w)
    float4 a16r[4];
#pragma unroll
    for (int kq = 0; kq < 4; ++kq)
        a16r[kq] = *(const float4*)&CtS[l * CT_ST + 16 * w + 4 * kq];

    // ple[p][i] = sum_{j<16} vs[j][i] * u[16p+15-j]
    {
        float s = 0.f;
#pragma unroll
        for (int j = 0; j < 16; ++j) s += VSS[j * NS + l] * uS[16 * w + 15 - j];
        pleS[w * NS + l] = s;
    }
    __syncthreads();

    // mini-scan: xb_p = A16*xb_{p-1} + ple[p-1], p = 1..3
    for (int p = 1; p < 4; ++p) {
        float4 x0q = *(const float4*)&xbS[(p - 1) * NS + 16 * w + 0];
        float4 x1q = *(const float4*)&xbS[(p - 1) * NS + 16 * w + 4];
        float4 x2q = *(const float4*)&xbS[(p - 1) * NS + 16 * w + 8];
        float4 x3q = *(const float4*)&xbS[(p - 1) * NS + 16 * w + 12];
        float s = a16r[0].x * x0q.x + a16r[0].y * x0q.y + a16r[0].z * x0q.z + a16r[0].w * x0q.w
                + a16r[1].x * x1q.x + a16r[1].y * x1q.y + a16r[1].z * x1q.z + a16r[1].w * x1q.w
                + a16r[2].x * x2q.x + a16r[2].y * x2q.y + a16r[2].z * x2q.z + a16r[2].w * x2q.w
                + a16r[3].x * x3q.x + a16r[3].y * x3q.y + a16r[3].z * x3q.z + a16r[3].w * x3q.w;
        partS[w * NS + l] = s;
        __syncthreads();
        if (w == 0) {
            float xn = partS[l] + partS[NS + l] + partS[2 * NS + l] + partS[3 * NS + l]
                     + pleS[(p - 1) * NS + l];
            xbS[p * NS + l] = xn;
        }
        __syncthreads();
    }

    // init per-wave state; then 16 barrier-free steps (paragraph w -> t in [16w,16w+16))
    xcW[w * NS + l] = xbS[w * NS + l];
    for (int s = 0; s < 16; ++s) {
        __threadfence_block();   // order sibling-lane xcW writes before reads
        const int t = 16 * w + s;
        float4 x0q = *(const float4*)&xcW[w * NS + 16 * q + 0];
        float4 x1q = *(const float4*)&xcW[w * NS + 16 * q + 4];
        float4 x2q = *(const float4*)&xcW[w * NS + 16 * q + 8];
        float4 x3q = *(const float4*)&xcW[w * NS + 16 * q + 12];
        float p0, p1, p2, p3;
        p0 = ar[0][0].x * x0q.x + ar[0][0].y * x0q.y + ar[0][0].z * x0q.z + ar[0][0].w * x0q.w
           + ar[0][1].x * x1q.x + ar[0][1].y * x1q.y + ar[0][1].z * x1q.z + ar[0][1].w * x1q.w
           + ar[0][2].x * x2q.x + ar[0][2].y * x2q.y + ar[0][2].z * x2q.z + ar[0][2].w * x2q.w
           + ar[0][3].x * x3q.x + ar[0][3].y * x3q.y + ar[0][3].z * x3q.z + ar[0][3].w * x3q.w;
        p1 = ar[1][0].x * x0q.x + ar[1][0].y * x0q.y + ar[1][0].z * x0q.z + ar[1][0].w * x0q.w
           + ar[1][1].x * x1q.x + ar[1][1].y * x1q.y + ar[1][1].z * x1q.z + ar[1][1].w * x1q.w
           + ar[1][2].x * x2q.x + ar[1][2].y * x2q.y + ar[1][2].z * x2q.z + ar[1][2].w * x2q.w
           + ar[1][3].x * x3q.x + ar[1][3].y * x3q.y + ar[1][3].z * x3q.z + ar[1][3].w * x3q.w;
        p2 = ar[2][0].x * x0q.x + ar[2][0].y * x0q.y + ar[2][0].z * x0q.z + ar[2][0].w * x0q.w
           + ar[2][1].x * x1q.x + ar[2][1].y * x1q.y + ar[2][1].z * x1q.z + ar[2][1].w * x1q.w
           + ar[2][2].x * x2q.x + ar[2][2].y * x2q.y + ar[2][2].z * x2q.z + ar[2][2].w * x2q.w
           + ar[2][3].x * x3q.x + ar[2][3].y * x3q.y + ar[2][3].z * x3q.z + ar[2][3].w * x3q.w;
        p3 = ar[3][0].x * x0q.x + ar[3][0].y * x0q.y + ar[3][0].z * x0q.z + ar[3][0].w * x0q.w
           + ar[3][1].x * x1q.x + ar[3][1].y * x1q.y + ar[3][1].z * x1q.z + ar[3][1].w * x1q.w
           + ar[3][2].x * x2q.x + ar[3][2].y * x2q.y + ar[3][2].z * x2q.z + ar[3][2].w * x2q.w
           + ar[3][3].x * x3q.x + ar[3][3].y * x3q.y + ar[3][3].z * x3q.z + ar[3][3].w * x3q.w;
        // butterfly over k-chunks (lanes l^16, l^32)
        p0 += __shfl_xor(p0, 16, 64); p1 += __shfl_xor(p1, 16, 64);
        p2 += __shfl_xor(p2, 16, 64); p3 += __shfl_xor(p3, 16, 64);
        p0 += __shfl_xor(p0, 32, 64); p1 += __shfl_xor(p1, 32, 64);
        p2 += __shfl_xor(p2, 32, 64); p3 += __shfl_xor(p3, 32, 64);
        const float ut = uS[t];
        p0 += bbr[0] * ut; p1 += bbr[1] * ut; p2 += bbr[2] * ut; p3 += bbr[3] * ut;
        const float xv = (q == 0) ? p0 : (q == 1) ? p1 : (q == 2) ? p2 : p3;
        const int row = r0 + 16 * q;
        xcW[w * NS + row] = xv;
        Xl[row * ST + t]  = xv;
    }
    __syncthreads();

    // phase2: stage C^T (gathered coalesced loads -> b128 writes)
    for (int rep = 0; rep < 8; ++rep) {
        const int ii = tid & 63;
        const int cg = (tid >> 6) + 4 * rep;   // 0..31
        float4 v;
        v.x = Cm[(4 * cg + 0) * NS + ii];
        v.y = Cm[(4 * cg + 1) * NS + ii];
        v.z = Cm[(4 * cg + 2) * NS + ii];
        v.w = Cm[(4 * cg + 3) * NS + ii];
        *(float4*)&CtS[ii * CT_ST + 4 * cg] = v;
    }
    __syncthreads();

    if (tid < 128) {
        const int tg = tid & 7, cg = tid >> 3;   // c0 = 8*cg, t0 = 8*tg
        float acc[8][8];
#pragma unroll
        for (int r = 0; r < 8; ++r)
#pragma unroll
            for (int c = 0; c < 8; ++c) acc[r][c] = 0.f;
#pragma unroll 4
        for (int ii = 0; ii < NS; ++ii) {
            float4 c01 = *(const float4*)&CtS[ii * CT_ST + 8 * cg + 0];
            float4 c23 = *(const float4*)&CtS[ii * CT_ST + 8 * cg + 4];
            float4 xa  = *(const float4*)&Xl[ii * ST + 8 * tg + 0];
            float4 xb  = *(const float4*)&Xl[ii * ST + 8 * tg + 4];
            float cv[8] = {c01.x, c01.y, c01.z, c01.w, c23.x, c23.y, c23.z, c23.w};
            float xv[8] = {xa.x, xa.y, xa.z, xa.w, xb.x, xb.y, xb.z, xb.w};
#pragma unroll
            for (int r = 0; r < 8; ++r)
#pragma unroll
                for (int c = 0; c < 8; ++c) acc[r][c] += cv[r] * xv[c];
        }
        const size_t obase = ((size_t)b * CH) * LSEQ + (size_t)m * SCH + 8 * tg;
#pragma unroll
        for (int r = 0; r < 8; ++r) {
            const int c = 8 * cg + r;
            const float dv = DS[c];
            float4 o1, o2;
            o1.x = acc[r][0] + dv * uS[8 * tg + 0];
            o1.y = acc[r][1] + dv * uS[8 * tg + 1];
            o1.z = acc[r][2] + dv * uS[8 * tg + 2];
            o1.w = acc[r][3] + dv * uS[8 * tg + 3];
            o2.x = acc[r][4] + dv * uS[8 * tg + 4];
            o2.y = acc[r][5] + dv * uS[8 * tg + 5];
            o2.z = acc[r][6] + dv * uS[8 * tg + 6];
            o2.w = acc[r][7] + dv * uS[8 * tg + 7];
            float* op = out + obase + (size_t)c * LSEQ;
            *(float4*)(op)     = o1;
            *(float4*)(op + 4) = o2;
        }
    }
}

// ---------------------------------------------------------------------------
// K3 fallback (R3 version, proven) — used if ws too small for A16.
// ---------------------------------------------------------------------------
__global__ __launch_bounds__(256) void k_main_fb(const float* __restrict__ u,
                                                 const float* __restrict__ Cm,
                                                 const float* __restrict__ Dv,
                                                 const float* __restrict__ ws,
                                                 float* __restrict__ out) {
    __shared__ __align__(16) float R0[NS * 65];
    __shared__ __align__(16) float Xl[NS * 68];
    __shared__ __align__(16) float BbS[NS];
    __shared__ __align__(16) float uS[SCH];
    __shared__ __align__(16) float DS[CH];
    __shared__ __align__(16) float xcS[NS];
    __shared__ __align__(16) float part[2][4 * NS];
    const int m = blockIdx.x, b = blockIdx.y;
    const int tid = threadIdx.x;
    const int i = tid & 63, q = tid >> 6;

    for (int o = tid; o < NS * NS; o += 256) {
        int r = o >> 6, c = o & 63;
        R0[r * 65 + c] = ws[WS_ABAR + o];
    }
    if (tid < NS) {
        BbS[tid] = ws[WS_BBAR + tid];
        uS[tid]  = u[b * LSEQ + m * SCH + tid];
        xcS[tid] = out[X0_IDX(b, m) + tid];
    }
    if (tid < CH) DS[tid] = Dv[tid];
    __syncthreads();

    float arow[16];
#pragma unroll
    for (int kk = 0; kk < 16; ++kk) arow[kk] = R0[i * 65 + 16 * q + kk];

    for (int t = 0; t < SCH; ++t) {
        float4 t0 = *(const float4*)(xcS + 16 * q + 0);
        float4 t1 = *(const float4*)(xcS + 16 * q + 4);
        float4 t2 = *(const float4*)(xcS + 16 * q + 8);
        float4 t3 = *(const float4*)(xcS + 16 * q + 12);
        float s = arow[0] * t0.x + arow[1] * t0.y + arow[2] * t0.z + arow[3] * t0.w
                + arow[4] * t1.x + arow[5] * t1.y + arow[6] * t1.z + arow[7] * t1.w
                + arow[8] * t2.x + arow[9] * t2.y + arow[10] * t2.z + arow[11] * t2.w
                + arow[12] * t3.x + arow[13] * t3.y + arow[14] * t3.z + arow[15] * t3.w;
        part[t & 1][q * 64 + i] = s;
        __syncthreads();
        float xn = part[t & 1][i] + part[t & 1][64 + i] + part[t & 1][128 + i]
                 + part[t & 1][192 + i] + BbS[i] * uS[t];
        xcS[i] = xn;
        if (q == 0) Xl[i * 68 + t] = xn;
    }
    __syncthreads();

    const int tq = tid & 7, c0 = tid >> 3;
    const int t0i = 8 * tq;
    float acc[4][8];
#pragma unroll
    for (int r = 0; r < 4; ++r)
#pragma unroll
        for (int tt = 0; tt < 8; ++tt) acc[r][tt] = 0.f;

    for (int half = 0; half < 2; ++half) {
        for (int o = tid; o < NS * NS; o += 256) {
            int cc = o >> 6, ii = o & 63;
            R0[cc * 65 + ii] = Cm[(half * NS + cc) * NS + ii];
        }
        __syncthreads();
        for (int ii = 0; ii < NS; ++ii) {
            float4 xa = *(const float4*)(Xl + ii * 68 + t0i);
            float4 xb = *(const float4*)(Xl + ii * 68 + t0i + 4);
#pragma unroll
            for (int rr = 0; rr < 2; ++rr) {
                float cv = R0[(c0 + 32 * rr) * 65 + ii];
                float* a = acc[half * 2 + rr];
                a[0] += cv * xa.x; a[1] += cv * xa.y; a[2] += cv * xa.z; a[3] += cv * xa.w;
                a[4] += cv * xb.x; a[5] += cv * xb.y; a[6] += cv * xb.z; a[7] += cv * xb.w;
            }
        }
        __syncthreads();
    }

    const size_t obase = ((size_t)b * CH) * LSEQ + (size_t)m * SCH + t0i;
#pragma unroll
    for (int r = 0; r < 4; ++r) {
        int c = c0 + 32 * r;
        float dv = DS[c];
        float4 o1, o2;
        o1.x = acc[r][0] + dv * uS[t0i + 0];
        o1.y = acc[r][1] + dv * uS[t0i + 1];
        o1.z = acc[r][2] + dv * uS[t0i + 2];
        o1.w = acc[r][3] + dv * uS[t0i + 3];
        o2.x = acc[r][4] + dv * uS[t0i + 4];
        o2.y = acc[r][5] + dv * uS[t0i + 5];
        o2.z = acc[r][6] + dv * uS[t0i + 6];
        o2.w = acc[r][7] + dv * uS[t0i + 7];
        float* op = out + obase + (size_t)c * LSEQ;
        *(float4*)(op)     = o1;
        *(float4*)(op + 4) = o2;
    }
}

extern "C" void kernel_launch(void* const* d_in, const int* in_sizes, int n_in,
                              void* d_out, int out_size, void* d_ws, size_t ws_size,
                              hipStream_t stream) {
    const float* u   = (const float*)d_in[0];
    const float* A   = (const float*)d_in[1];
    const float* Bv  = (const float*)d_in[2];
    const float* Cm  = (const float*)d_in[3];
    const float* Dv  = (const float*)d_in[4];
    const float* dtp = (const float*)d_in[5];
    float* ws  = (float*)d_ws;
    float* out = (float*)d_out;

    const int big = (ws_size >= (size_t)(WS_A16 + NS * NS) * sizeof(float)) ? 1 : 0;
    k_setup<<<1, 256, 0, stream>>>(A, Bv, dtp, ws, big);
    k_bound<<<NB, 256, 0, stream>>>(u, ws, out);
    if (big)
        k_main_par<<<dim3(MCH, NB), 256, 0, stream>>>(u, Cm, Dv, ws, out);
    else
        k_main_fb<<<dim3(MCH, NB), 256, 0, stream>>>(u, Cm, Dv, ws, out);
}

// Round 5
// 167.734 us; speedup vs baseline: 1.4952x; 1.1464x over previous
//
#include <hip/hip_runtime.h>

#define NS   64      // state dim
#define CH   128     // channels
#define LSEQ 4096    // sequence length
#define NB   16      // batch
#define SCH  64      // chunk size
#define MCH  64      // number of chunks (LSEQ/SCH)
#define ST   68      // padded LDS row stride (68*4 = 272B, 16B-aligned)
#define CT_ST 132    // C^T LDS stride

// ws float offsets (max 12352 floats = 48.3 KB; ws_size proven >= 311 KB in R2)
#define WS_ABAR 0          // 64*64 A_bar row-major
#define WS_A16  4096       // 64*64 A_bar^16
#define WS_VS   8192       // 64*64 vs[j*64+i] = (A_bar^j B_bar)[i]
#define WS_BBAR 12288      // 64

// X0 stash in d_out: slot (b,m) later written only by k_main block (m,b).
#define X0_IDX(b, m) (((size_t)(b) * CH) * LSEQ + (size_t)(m) * SCH)

#define FMA44(av, bv)                                                          \
    a0.x += av.x * bv.x; a0.y += av.x * bv.y; a0.z += av.x * bv.z; a0.w += av.x * bv.w; \
    a1.x += av.y * bv.x; a1.y += av.y * bv.y; a1.z += av.y * bv.z; a1.w += av.y * bv.w; \
    a2.x += av.z * bv.x; a2.y += av.z * bv.y; a2.z += av.z * bv.z; a2.w += av.z * bv.w; \
    a3.x += av.w * bv.x; a3.y += av.w * bv.y; a3.z += av.w * bv.z; a3.w += av.w * bv.w;

// ---------------------------------------------------------------------------
// K1: merged setup + boundary scan. 16 blocks (one per batch); each block
// redundantly computes A_bar/B_bar/vs/A^16/A^64 (identical bits), block 0
// also writes them to ws for k_main. Then each block runs its batch's
// 64-step chunk scan, stashing X0 into d_out.
// ---------------------------------------------------------------------------
__global__ __launch_bounds__(256) void k_sb(const float* __restrict__ u,
                                            const float* __restrict__ A,
                                            const float* __restrict__ Bv,
                                            const float* __restrict__ dtp,
                                            float* __restrict__ ws,
                                            float* __restrict__ out) {
    __shared__ __align__(16) float Mrow[NS * ST];        // pair0 row-major
    __shared__ __align__(16) float Mcol[(NS + 1) * ST];  // pair0 transposed; row64 = B_bar
    __shared__ __align__(16) float Nrow[NS * ST];        // T1; pair1 row; later uT
    __shared__ __align__(16) float Ncol[NS * ST];        // T2^T; pair1 transposed
    __shared__ __align__(16) float VT[NS * ST];          // VT[k][j] = vs[j][k]
    __shared__ __align__(16) float vsS[NS * NS];         // vs[j][i] row-major
    __shared__ __align__(16) float xleS[MCH * NS];
    __shared__ __align__(16) float part[2][4 * NS];
    __shared__ __align__(16) float bcol[NS];
    __shared__ float rdiag[NS], xcS[NS], vtmp[NS];
    const int tid = threadIdx.x;
    const int b = blockIdx.x;
    const float dt = dtp[0];
    const float hdt = 0.5f * dt;

    for (int o = tid; o < NS * ST; o += 256) { Mrow[o] = 0.f; Nrow[o] = 0.f; Ncol[o] = 0.f; VT[o] = 0.f; }
    for (int o = tid; o < (NS + 1) * ST; o += 256) Mcol[o] = 0.f;
    __syncthreads();

    // T1 = I - hdt*A (row-major, lower-tri); T2^T (upper storage). A lower-tri.
    for (int o = tid; o < NS * NS; o += 256) {
        int i = o >> 6, k = o & 63;
        float a = A[o];
        float d = (i == k) ? 1.0f : 0.0f;
        Nrow[i * ST + k] = d - hdt * a;
        Ncol[k * ST + i] = d + hdt * a;
    }
    if (tid < NS) bcol[tid] = dt * Bv[tid];
    __syncthreads();
    if (tid < NS) rdiag[tid] = 1.0f / Nrow[tid * ST + tid];
    __syncthreads();

    // blocked forward substitution: lane j (<64) solves column j of
    // A_bar = inv(T1)*T2 into Mcol row j; thread 64 solves B_bar into row 64.
    // 4 rows per LDS round-trip; x-history reads are lane-local b128.
    if (tid <= NS) {
        const int j = tid;
        float* xrow = &Mcol[j * ST];
        for (int I = 0; I < 16; ++I) {
            const int i0 = 4 * I;
            float4 t2 = (j < NS) ? *(const float4*)&Ncol[j * ST + i0]
                                 : *(const float4*)&bcol[i0];
            float a0 = t2.x, a1 = t2.y, a2 = t2.z, a3 = t2.w;
            for (int k = 0; k < i0; k += 4) {
                float4 xk = *(const float4*)&xrow[k];
                float4 n0 = *(const float4*)&Nrow[(i0 + 0) * ST + k];
                float4 n1 = *(const float4*)&Nrow[(i0 + 1) * ST + k];
                float4 n2 = *(const float4*)&Nrow[(i0 + 2) * ST + k];
                float4 n3 = *(const float4*)&Nrow[(i0 + 3) * ST + k];
                a0 -= n0.x * xk.x + n0.y * xk.y + n0.z * xk.z + n0.w * xk.w;
                a1 -= n1.x * xk.x + n1.y * xk.y + n1.z * xk.z + n1.w * xk.w;
                a2 -= n2.x * xk.x + n2.y * xk.y + n2.z * xk.z + n2.w * xk.w;
                a3 -= n3.x * xk.x + n3.y * xk.y + n3.z * xk.z + n3.w * xk.w;
            }
            float4 rd  = *(const float4*)&rdiag[i0];
            float4 nb1 = *(const float4*)&Nrow[(i0 + 1) * ST + i0];
            float4 nb2 = *(const float4*)&Nrow[(i0 + 2) * ST + i0];
            float4 nb3 = *(const float4*)&Nrow[(i0 + 3) * ST + i0];
            float x0 = a0 * rd.x;
            float x1 = (a1 - nb1.x * x0) * rd.y;
            float x2 = (a2 - nb2.x * x0 - nb2.y * x1) * rd.z;
            float x3 = (a3 - nb3.x * x0 - nb3.y * x1 - nb3.z * x2) * rd.w;
            float4 xw = {x0, x1, x2, x3};
            *(float4*)&xrow[i0] = xw;
        }
    }
    __syncthreads();

    // transpose Mcol -> Mrow (A_bar row-major); block 0 stores ABAR + BBAR
    {
        const int i0 = 4 * (tid >> 4), j0 = 4 * (tid & 15);
        float4 r0 = *(const float4*)&Mcol[(j0 + 0) * ST + i0];
        float4 r1 = *(const float4*)&Mcol[(j0 + 1) * ST + i0];
        float4 r2 = *(const float4*)&Mcol[(j0 + 2) * ST + i0];
        float4 r3 = *(const float4*)&Mcol[(j0 + 3) * ST + i0];
        float4 w0 = {r0.x, r1.x, r2.x, r3.x};
        float4 w1 = {r0.y, r1.y, r2.y, r3.y};
        float4 w2 = {r0.z, r1.z, r2.z, r3.z};
        float4 w3 = {r0.w, r1.w, r2.w, r3.w};
        *(float4*)&Mrow[(i0 + 0) * ST + j0] = w0;
        *(float4*)&Mrow[(i0 + 1) * ST + j0] = w1;
        *(float4*)&Mrow[(i0 + 2) * ST + j0] = w2;
        *(float4*)&Mrow[(i0 + 3) * ST + j0] = w3;
        if (b == 0) {
            *(float4*)&ws[WS_ABAR + (i0 + 0) * NS + j0] = w0;
            *(float4*)&ws[WS_ABAR + (i0 + 1) * NS + j0] = w1;
            *(float4*)&ws[WS_ABAR + (i0 + 2) * NS + j0] = w2;
            *(float4*)&ws[WS_ABAR + (i0 + 3) * NS + j0] = w3;
        }
    }
    if (b == 0 && tid < 16)
        *(float4*)&ws[WS_BBAR + 4 * tid] = *(const float4*)&Mcol[NS * ST + 4 * tid];
    __syncthreads();

    // seed vs[0..3] via 3 register matvecs (wave 0 only)
    if ((tid >> 6) == 0) {
        const int i = tid;
        float v = Mcol[NS * ST + i];   // B_bar[i]
        vtmp[i] = v;
        VT[i * ST + 0] = v;
        for (int j = 1; j < 4; ++j) {
            __threadfence_block();
            float s = 0.f;
            for (int k = 0; k < NS; k += 4) {
                float4 ar = *(const float4*)&Mrow[i * ST + k];
                float4 vv = *(const float4*)&vtmp[k];
                s += ar.x * vv.x + ar.y * vv.y + ar.z * vv.z + ar.w * vv.w;
            }
            __threadfence_block();
            vtmp[i] = s;
            VT[i * ST + j] = s;
        }
    }
    __syncthreads();

    // doubling chain: 6 squarings; expansions at m=4,8,16,32; A^16 saved at s=4
    float *cm = Mrow, *cmt = Mcol, *nm = Nrow, *nmt = Ncol;
    const int w4 = tid >> 6, l = tid & 63;
    const int si0 = 16 * w4 + 4 * (l >> 4);
    const int sj0 = 4 * (l & 15);
    const int skmax = 16 * (w4 + 1);
    for (int s = 1; s <= 6; ++s) {
        {   // squaring: nm = cm*cm (wave-uniform kmax, zeros handle triangle)
            float4 a0 = {0,0,0,0}, a1 = {0,0,0,0}, a2 = {0,0,0,0}, a3 = {0,0,0,0};
            for (int k = 0; k < skmax; k += 4) {
                float4 av0 = *(const float4*)&cmt[(k + 0) * ST + si0];
                float4 bv0 = *(const float4*)&cm [(k + 0) * ST + sj0];
                float4 av1 = *(const float4*)&cmt[(k + 1) * ST + si0];
                float4 bv1 = *(const float4*)&cm [(k + 1) * ST + sj0];
                float4 av2 = *(const float4*)&cmt[(k + 2) * ST + si0];
                float4 bv2 = *(const float4*)&cm [(k + 2) * ST + sj0];
                float4 av3 = *(const float4*)&cmt[(k + 3) * ST + si0];
                float4 bv3 = *(const float4*)&cm [(k + 3) * ST + sj0];
                FMA44(av0, bv0)
                FMA44(av1, bv1)
                FMA44(av2, bv2)
                FMA44(av3, bv3)
            }
            *(float4*)&nm[(si0 + 0) * ST + sj0] = a0;
            *(float4*)&nm[(si0 + 1) * ST + sj0] = a1;
            *(float4*)&nm[(si0 + 2) * ST + sj0] = a2;
            *(float4*)&nm[(si0 + 3) * ST + sj0] = a3;
            float4 t0 = {a0.x, a1.x, a2.x, a3.x};
            float4 t1 = {a0.y, a1.y, a2.y, a3.y};
            float4 t2 = {a0.z, a1.z, a2.z, a3.z};
            float4 t3 = {a0.w, a1.w, a2.w, a3.w};
            *(float4*)&nmt[(sj0 + 0) * ST + si0] = t0;
            *(float4*)&nmt[(sj0 + 1) * ST + si0] = t1;
            *(float4*)&nmt[(sj0 + 2) * ST + si0] = t2;
            *(float4*)&nmt[(sj0 + 3) * ST + si0] = t3;
        }
        __syncthreads();
        { float* t = cm; cm = nm; nm = t; t = cmt; cmt = nmt; nmt = t; }
        if (s == 4 && b == 0) {   // cm == A^16 row-major
            for (int o = tid; o < (NS * NS) / 4; o += 256) {
                int r = o >> 4, c4 = (o & 15) * 4;
                *(float4*)&ws[WS_A16 + r * NS + c4] = *(const float4*)&cm[r * ST + c4];
            }
        }
        if (s >= 2 && s <= 5) {
            const int m = 1 << s;
            if (tid < 4 * m) {
                const int vi = 4 * (tid & 15), vj = 4 * (tid >> 4);
                float4 a0 = {0,0,0,0}, a1 = {0,0,0,0}, a2 = {0,0,0,0}, a3 = {0,0,0,0};
                for (int k = 0; k < NS; k += 2) {
                    float4 av  = *(const float4*)&cmt[k * ST + vi];
                    float4 bv  = *(const float4*)&VT [k * ST + vj];
                    float4 av2 = *(const float4*)&cmt[(k + 1) * ST + vi];
                    float4 bv2 = *(const float4*)&VT [(k + 1) * ST + vj];
                    FMA44(av, bv)
                    FMA44(av2, bv2)
                }
                *(float4*)&VT[(vi + 0) * ST + vj + m] = a0;
                *(float4*)&VT[(vi + 1) * ST + vj + m] = a1;
                *(float4*)&VT[(vi + 2) * ST + vj + m] = a2;
                *(float4*)&VT[(vi + 3) * ST + vj + m] = a3;
            }
        }
        __syncthreads();
    }
    // cm/cmt = A^64 (in Mrow/Mcol); Nrow/Ncol dead.

    // VT -> vsS transpose; block 0 stores ws VS
    {
        const int it = tid >> 4, jt = tid & 15;
        const int i0 = 4 * it, j0 = 4 * jt;
        float4 v0 = *(const float4*)&VT[(i0 + 0) * ST + j0];
        float4 v1 = *(const float4*)&VT[(i0 + 1) * ST + j0];
        float4 v2 = *(const float4*)&VT[(i0 + 2) * ST + j0];
        float4 v3 = *(const float4*)&VT[(i0 + 3) * ST + j0];
        float4 w0 = {v0.x, v1.x, v2.x, v3.x};   // vs[j0+0][i0..i0+3]
        float4 w1 = {v0.y, v1.y, v2.y, v3.y};
        float4 w2 = {v0.z, v1.z, v2.z, v3.z};
        float4 w3 = {v0.w, v1.w, v2.w, v3.w};
        *(float4*)&vsS[(j0 + 0) * NS + i0] = w0;
        *(float4*)&vsS[(j0 + 1) * NS + i0] = w1;
        *(float4*)&vsS[(j0 + 2) * NS + i0] = w2;
        *(float4*)&vsS[(j0 + 3) * NS + i0] = w3;
        if (b == 0) {
            *(float4*)&ws[WS_VS + (j0 + 0) * NS + i0] = w0;
            *(float4*)&ws[WS_VS + (j0 + 1) * NS + i0] = w1;
            *(float4*)&ws[WS_VS + (j0 + 2) * NS + i0] = w2;
            *(float4*)&ws[WS_VS + (j0 + 3) * NS + i0] = w3;
        }
    }

    // stage u transposed into dead Nrow: uT[jj][m] = u[b][m*64 + 63-jj]
    {
        const int jj = tid & 63;
        for (int rep = 0; rep < 4; ++rep) {
            const int m0 = 4 * (tid >> 6) + 16 * rep;
            float4 v;
            v.x = u[b * LSEQ + (m0 + 0) * SCH + 63 - jj];
            v.y = u[b * LSEQ + (m0 + 1) * SCH + 63 - jj];
            v.z = u[b * LSEQ + (m0 + 2) * SCH + 63 - jj];
            v.w = u[b * LSEQ + (m0 + 3) * SCH + 63 - jj];
            *(float4*)&Nrow[jj * ST + m0] = v;
        }
    }
    // A^64 rows into registers (from Mrow)
    const int i = tid & 63, q = tid >> 6;
    float4 a64[4];
#pragma unroll
    for (int kq = 0; kq < 4; ++kq)
        a64[kq] = *(const float4*)&Mrow[i * ST + 16 * q + 4 * kq];
    __syncthreads();

    // xle[m][i] = sum_j vs[j][i] * uT[j][m]
    {
        const int ig = tid & 15, mg = tid >> 4;
        float4 a0 = {0,0,0,0}, a1 = {0,0,0,0}, a2 = {0,0,0,0}, a3 = {0,0,0,0};
        for (int j = 0; j < NS; j += 2) {
            float4 am  = *(const float4*)&Nrow[j * ST + 4 * mg];
            float4 bi  = *(const float4*)&vsS[j * NS + 4 * ig];
            float4 am2 = *(const float4*)&Nrow[(j + 1) * ST + 4 * mg];
            float4 bi2 = *(const float4*)&vsS[(j + 1) * NS + 4 * ig];
            FMA44(am, bi)
            FMA44(am2, bi2)
        }
        *(float4*)&xleS[(4 * mg + 0) * NS + 4 * ig] = a0;
        *(float4*)&xleS[(4 * mg + 1) * NS + 4 * ig] = a1;
        *(float4*)&xleS[(4 * mg + 2) * NS + 4 * ig] = a2;
        *(float4*)&xleS[(4 * mg + 3) * NS + 4 * ig] = a3;
    }
    if (tid < NS) xcS[tid] = 0.f;
    __syncthreads();

    // 64-step chunk scan (proven R2-R4 structure)
    for (int m = 0; m < MCH; ++m) {
        if (q == 0) out[X0_IDX(b, m) + i] = xcS[i];
        float4 t0 = *(const float4*)(xcS + 16 * q + 0);
        float4 t1 = *(const float4*)(xcS + 16 * q + 4);
        float4 t2 = *(const float4*)(xcS + 16 * q + 8);
        float4 t3 = *(const float4*)(xcS + 16 * q + 12);
        float s = a64[0].x * t0.x + a64[0].y * t0.y + a64[0].z * t0.z + a64[0].w * t0.w
                + a64[1].x * t1.x + a64[1].y * t1.y + a64[1].z * t1.z + a64[1].w * t1.w
                + a64[2].x * t2.x + a64[2].y * t2.y + a64[2].z * t2.z + a64[2].w * t2.w
                + a64[3].x * t3.x + a64[3].y * t3.y + a64[3].z * t3.z + a64[3].w * t3.w;
        part[m & 1][q * 64 + i] = s;
        __syncthreads();
        float xn = part[m & 1][i] + part[m & 1][64 + i] + part[m & 1][128 + i]
                 + part[m & 1][192 + i] + xleS[m * 64 + i];
        xcS[i] = xn;   // all waves write identical bits
    }
}

// ---------------------------------------------------------------------------
// K2: main. Phase 1 = A^16 mini-scan + per-wave paragraph recurrence (R4,
// proven). Phase 2 = C@X on ALL 4 waves (4c x 8t per lane).
// ---------------------------------------------------------------------------
__global__ __launch_bounds__(256) void k_main2(const float* __restrict__ u,
                                               const float* __restrict__ Cm,
                                               const float* __restrict__ Dv,
                                               const float* __restrict__ ws,
                                               float* __restrict__ out) {
    __shared__ __align__(16) float Xl[NS * ST];       // A_bar staging, then X[i][t]
    __shared__ __align__(16) float CtS[NS * CT_ST];   // A16 staging, then C^T
    __shared__ __align__(16) float xcW[4 * NS];
    __shared__ __align__(16) float xbS[4 * NS];
    __shared__ __align__(16) float VSS[16 * NS];
    __shared__ __align__(16) float pleS[4 * NS];
    __shared__ __align__(16) float partS[4 * NS];
    __shared__ float uS[SCH], DS[CH], bbS[NS];
    const int m = blockIdx.x, b = blockIdx.y;
    const int tid = threadIdx.x;
    const int l = tid & 63, w = tid >> 6;

    for (int o = tid; o < (NS * NS) / 4; o += 256) {
        int r = o >> 4, c4 = (o & 15) * 4;
        *(float4*)&Xl[r * ST + c4]     = *(const float4*)&ws[WS_ABAR + r * NS + c4];
        *(float4*)&CtS[r * CT_ST + c4] = *(const float4*)&ws[WS_A16 + r * NS + c4];
    }
    for (int o = tid; o < 16 * NS; o += 256) VSS[o] = ws[WS_VS + o];
    if (tid < NS) {
        uS[tid]  = u[b * LSEQ + m * SCH + tid];
        bbS[tid] = ws[WS_BBAR + tid];
        xbS[tid] = out[X0_IDX(b, m) + tid];
    }
    if (tid < CH) DS[tid] = Dv[tid];
    __syncthreads();

    const int r0 = l & 15, q = l >> 4;
    float4 ar[4][4];
#pragma unroll
    for (int b4 = 0; b4 < 4; ++b4)
#pragma unroll
        for (int kq = 0; kq < 4; ++kq)
            ar[b4][kq] = *(const float4*)&Xl[(r0 + 16 * b4) * ST + 16 * q + 4 * kq];
    float bbr[4];
#pragma unroll
    for (int b4 = 0; b4 < 4; ++b4) bbr[b4] = bbS[r0 + 16 * b4];
    float4 a16r[4];
#pragma unroll
    for (int kq = 0; kq < 4; ++kq)
        a16r[kq] = *(const float4*)&CtS[l * CT_ST + 16 * w + 4 * kq];

    {
        float s = 0.f;
#pragma unroll
        for (int j = 0; j < 16; ++j) s += VSS[j * NS + l] * uS[16 * w + 15 - j];
        pleS[w * NS + l] = s;
    }
    __syncthreads();

    for (int p = 1; p < 4; ++p) {
        float4 x0q = *(const float4*)&xbS[(p - 1) * NS + 16 * w + 0];
        float4 x1q = *(const float4*)&xbS[(p - 1) * NS + 16 * w + 4];
        float4 x2q = *(const float4*)&xbS[(p - 1) * NS + 16 * w + 8];
        float4 x3q = *(const float4*)&xbS[(p - 1) * NS + 16 * w + 12];
        float s = a16r[0].x * x0q.x + a16r[0].y * x0q.y + a16r[0].z * x0q.z + a16r[0].w * x0q.w
                + a16r[1].x * x1q.x + a16r[1].y * x1q.y + a16r[1].z * x1q.z + a16r[1].w * x1q.w
                + a16r[2].x * x2q.x + a16r[2].y * x2q.y + a16r[2].z * x2q.z + a16r[2].w * x2q.w
                + a16r[3].x * x3q.x + a16r[3].y * x3q.y + a16r[3].z * x3q.z + a16r[3].w * x3q.w;
        partS[w * NS + l] = s;
        __syncthreads();
        if (w == 0) {
            float xn = partS[l] + partS[NS + l] + partS[2 * NS + l] + partS[3 * NS + l]
                     + pleS[(p - 1) * NS + l];
            xbS[p * NS + l] = xn;
        }
        __syncthreads();
    }

    xcW[w * NS + l] = xbS[w * NS + l];
    for (int s = 0; s < 16; ++s) {
        __threadfence_block();
        const int t = 16 * w + s;
        float4 x0q = *(const float4*)&xcW[w * NS + 16 * q + 0];
        float4 x1q = *(const float4*)&xcW[w * NS + 16 * q + 4];
        float4 x2q = *(const float4*)&xcW[w * NS + 16 * q + 8];
        float4 x3q = *(const float4*)&xcW[w * NS + 16 * q + 12];
        float p0, p1, p2, p3;
        p0 = ar[0][0].x * x0q.x + ar[0][0].y * x0q.y + ar[0][0].z * x0q.z + ar[0][0].w * x0q.w
           + ar[0][1].x * x1q.x + ar[0][1].y * x1q.y + ar[0][1].z * x1q.z + ar[0][1].w * x1q.w
           + ar[0][2].x * x2q.x + ar[0][2].y * x2q.y + ar[0][2].z * x2q.z + ar[0][2].w * x2q.w
           + ar[0][3].x * x3q.x + ar[0][3].y * x3q.y + ar[0][3].z * x3q.z + ar[0][3].w * x3q.w;
        p1 = ar[1][0].x * x0q.x + ar[1][0].y * x0q.y + ar[1][0].z * x0q.z + ar[1][0].w * x0q.w
           + ar[1][1].x * x1q.x + ar[1][1].y * x1q.y + ar[1][1].z * x1q.z + ar[1][1].w * x1q.w
           + ar[1][2].x * x2q.x + ar[1][2].y * x2q.y + ar[1][2].z * x2q.z + ar[1][2].w * x2q.w
           + ar[1][3].x * x3q.x + ar[1][3].y * x3q.y + ar[1][3].z * x3q.z + ar[1][3].w * x3q.w;
        p2 = ar[2][0].x * x0q.x + ar[2][0].y * x0q.y + ar[2][0].z * x0q.z + ar[2][0].w * x0q.w
           + ar[2][1].x * x1q.x + ar[2][1].y * x1q.y + ar[2][1].z * x1q.z + ar[2][1].w * x1q.w
           + ar[2][2].x * x2q.x + ar[2][2].y * x2q.y + ar[2][2].z * x2q.z + ar[2][2].w * x2q.w
           + ar[2][3].x * x3q.x + ar[2][3].y * x3q.y + ar[2][3].z * x3q.z + ar[2][3].w * x3q.w;
        p3 = ar[3][0].x * x0q.x + ar[3][0].y * x0q.y + ar[3][0].z * x0q.z + ar[3][0].w * x0q.w
           + ar[3][1].x * x1q.x + ar[3][1].y * x1q.y + ar[3][1].z * x1q.z + ar[3][1].w * x1q.w
           + ar[3][2].x * x2q.x + ar[3][2].y * x2q.y + ar[3][2].z * x2q.z + ar[3][2].w * x2q.w
           + ar[3][3].x * x3q.x + ar[3][3].y * x3q.y + ar[3][3].z * x3q.z + ar[3][3].w * x3q.w;
        p0 += __shfl_xor(p0, 16, 64); p1 += __shfl_xor(p1, 16, 64);
        p2 += __shfl_xor(p2, 16, 64); p3 += __shfl_xor(p3, 16, 64);
        p0 += __shfl_xor(p0, 32, 64); p1 += __shfl_xor(p1, 32, 64);
        p2 += __shfl_xor(p2, 32, 64); p3 += __shfl_xor(p3, 32, 64);
        const float ut = uS[t];
        p0 += bbr[0] * ut; p1 += bbr[1] * ut; p2 += bbr[2] * ut; p3 += bbr[3] * ut;
        const float xv = (q == 0) ? p0 : (q == 1) ? p1 : (q == 2) ? p2 : p3;
        const int row = r0 + 16 * q;
        xcW[w * NS + row] = xv;
        Xl[row * ST + t]  = xv;
    }
    __syncthreads();

    // phase2: stage C^T
    for (int rep = 0; rep < 8; ++rep) {
        const int ii = tid & 63;
        const int cg = (tid >> 6) + 4 * rep;   // 0..31
        float4 v;
        v.x = Cm[(4 * cg + 0) * NS + ii];
        v.y = Cm[(4 * cg + 1) * NS + ii];
        v.z = Cm[(4 * cg + 2) * NS + ii];
        v.w = Cm[(4 * cg + 3) * NS + ii];
        *(float4*)&CtS[ii * CT_ST + 4 * cg] = v;
    }
    __syncthreads();

    // Y = C@X + D*u : all 4 waves, 4 channels x 8 timesteps per lane
    {
        const int tg = tid & 7, cq = tid >> 3;   // t0 = 8*tg, c0 = 4*cq
        float acc[4][8];
#pragma unroll
        for (int r = 0; r < 4; ++r)
#pragma unroll
            for (int c = 0; c < 8; ++c) acc[r][c] = 0.f;
#pragma unroll 4
        for (int ii = 0; ii < NS; ++ii) {
            float4 cv = *(const float4*)&CtS[ii * CT_ST + 4 * cq];
            float4 xa = *(const float4*)&Xl[ii * ST + 8 * tg + 0];
            float4 xb = *(const float4*)&Xl[ii * ST + 8 * tg + 4];
            float cr[4] = {cv.x, cv.y, cv.z, cv.w};
            float xv[8] = {xa.x, xa.y, xa.z, xa.w, xb.x, xb.y, xb.z, xb.w};
#pragma unroll
            for (int r = 0; r < 4; ++r)
#pragma unroll
                for (int c = 0; c < 8; ++c) acc[r][c] += cr[r] * xv[c];
        }
        const size_t obase = ((size_t)b * CH) * LSEQ + (size_t)m * SCH + 8 * tg;
#pragma unroll
        for (int r = 0; r < 4; ++r) {
            const int c = 4 * cq + r;
            const float dv = DS[c];
            float4 o1, o2;
            o1.x = acc[r][0] + dv * uS[8 * tg + 0];
            o1.y = acc[r][1] + dv * uS[8 * tg + 1];
            o1.z = acc[r][2] + dv * uS[8 * tg + 2];
            o1.w = acc[r][3] + dv * uS[8 * tg + 3];
            o2.x = acc[r][4] + dv * uS[8 * tg + 4];
            o2.y = acc[r][5] + dv * uS[8 * tg + 5];
            o2.z = acc[r][6] + dv * uS[8 * tg + 6];
            o2.w = acc[r][7] + dv * uS[8 * tg + 7];
            float* op = out + obase + (size_t)c * LSEQ;
            *(float4*)(op)     = o1;
            *(float4*)(op + 4) = o2;
        }
    }
}

extern "C" void kernel_launch(void* const* d_in, const int* in_sizes, int n_in,
                              void* d_out, int out_size, void* d_ws, size_t ws_size,
                              hipStream_t stream) {
    const float* u   = (const float*)d_in[0];
    const float* A   = (const float*)d_in[1];
    const float* Bv  = (const float*)d_in[2];
    const float* Cm  = (const float*)d_in[3];
    const float* Dv  = (const float*)d_in[4];
    const float* dtp = (const float*)d_in[5];
    float* ws  = (float*)d_ws;
    float* out = (float*)d_out;

    k_sb<<<NB, 256, 0, stream>>>(u, A, Bv, dtp, ws, out);
    k_main2<<<dim3(MCH, NB), 256, 0, stream>>>(u, Cm, Dv, ws, out);
}

// Round 6
// 160.447 us; speedup vs baseline: 1.5631x; 1.0454x over previous
//
#include <hip/hip_runtime.h>

#define NS   64      // state dim
#define CH   128     // channels
#define LSEQ 4096    // sequence length
#define NB   16      // batch
#define SCH  64      // chunk size
#define MCH  64      // number of chunks (LSEQ/SCH)
#define ST   68      // padded LDS row stride (68*4 = 272B, 16B-aligned)
#define CP   128     // C^T pool stride (reads are uniform-row -> conflict-free)

// ws float offsets
#define WS_ABAR 0          // 64*64 A_bar row-major
#define WS_A16  4096       // 64*64 A_bar^16
#define WS_VS   8192       // 64*64 vs[j*64+i]
#define WS_BBAR 12288      // 64

// X0 stash in d_out: slot (b,m) later written only by k_main block (m,b).
#define X0_IDX(b, m) (((size_t)(b) * CH) * LSEQ + (size_t)(m) * SCH)

// k_main2 pool aliasing (floats): phase1 scratch + A16, then C^T (8192 f)
#define P_VSS  0
#define P_XCW  1024
#define P_XBS  1280
#define P_PLE  1536
#define P_PART 1792
#define P_A16  2048

#define FMA44(av, bv)                                                          \
    a0.x += av.x * bv.x; a0.y += av.x * bv.y; a0.z += av.x * bv.z; a0.w += av.x * bv.w; \
    a1.x += av.y * bv.x; a1.y += av.y * bv.y; a1.z += av.y * bv.z; a1.w += av.y * bv.w; \
    a2.x += av.z * bv.x; a2.y += av.z * bv.y; a2.z += av.z * bv.z; a2.w += av.z * bv.w; \
    a3.x += av.w * bv.x; a3.y += av.w * bv.y; a3.z += av.w * bv.z; a3.w += av.w * bv.w;

// ---------------------------------------------------------------------------
// K1: merged setup + boundary scan, 512 threads. Waves 0-3: squarings
// (constant-trip k=0..63, unrolled). Waves 4-7: concurrent vs-expansions.
// Substitution holds column history in registers (no LDS RT in the chain).
// ---------------------------------------------------------------------------
__global__ __launch_bounds__(512) void k_sb(const float* __restrict__ u,
                                            const float* __restrict__ A,
                                            const float* __restrict__ Bv,
                                            const float* __restrict__ dtp,
                                            float* __restrict__ ws,
                                            float* __restrict__ out) {
    __shared__ __align__(16) float Mrow[NS * ST];        // A_bar row-major / ping-pong
    __shared__ __align__(16) float Mcol[(NS + 1) * ST];  // transposed; row 64 = B_bar
    __shared__ __align__(16) float Nrow[NS * ST];        // T1 rows; ping-pong; later uT
    __shared__ __align__(16) float Ncol[NS * ST];        // T2^T; ping-pong
    __shared__ __align__(16) float VT[NS * ST];          // VT[k][j] = vs[j][k]
    __shared__ __align__(16) float vsS[NS * NS];         // vs[j][i]
    __shared__ __align__(16) float xleS[MCH * NS];
    __shared__ __align__(16) float part[2][4 * NS];
    __shared__ __align__(16) float bcol[NS];
    __shared__ float rdiag[NS], xcS[NS];
    const int tid = threadIdx.x;
    const int b = blockIdx.x;
    const float dt = dtp[0];
    const float hdt = 0.5f * dt;

    for (int o = tid; o < NS * ST; o += 512) { Mrow[o] = 0.f; Nrow[o] = 0.f; Ncol[o] = 0.f; VT[o] = 0.f; }
    for (int o = tid; o < (NS + 1) * ST; o += 512) Mcol[o] = 0.f;
    __syncthreads();

    for (int o = tid; o < NS * NS; o += 512) {
        int i = o >> 6, k = o & 63;
        float a = A[o];
        float d = (i == k) ? 1.0f : 0.0f;
        Nrow[i * ST + k] = d - hdt * a;   // T1
        Ncol[k * ST + i] = d + hdt * a;   // T2^T
    }
    if (tid < NS) {
        bcol[tid]  = dt * Bv[tid];
        rdiag[tid] = 1.0f / (1.0f - hdt * A[tid * NS + tid]);
    }
    __syncthreads();

    // forward substitution, column j in registers (lane j; tid==64 -> B_bar)
    if (tid <= NS) {
        float xr[NS];
        const float* t2b = (tid < NS) ? &Ncol[tid * ST] : bcol;
#pragma unroll
        for (int I = 0; I < 16; ++I) {
            const int i0 = 4 * I;
            float4 t2 = *(const float4*)&t2b[i0];
            float a0 = t2.x, a1 = t2.y, a2 = t2.z, a3 = t2.w;
#pragma unroll
            for (int k = 0; k < i0; k += 4) {
                float4 n0 = *(const float4*)&Nrow[(i0 + 0) * ST + k];
                float4 n1 = *(const float4*)&Nrow[(i0 + 1) * ST + k];
                float4 n2 = *(const float4*)&Nrow[(i0 + 2) * ST + k];
                float4 n3 = *(const float4*)&Nrow[(i0 + 3) * ST + k];
                a0 -= n0.x * xr[k] + n0.y * xr[k + 1] + n0.z * xr[k + 2] + n0.w * xr[k + 3];
                a1 -= n1.x * xr[k] + n1.y * xr[k + 1] + n1.z * xr[k + 2] + n1.w * xr[k + 3];
                a2 -= n2.x * xr[k] + n2.y * xr[k + 1] + n2.z * xr[k + 2] + n2.w * xr[k + 3];
                a3 -= n3.x * xr[k] + n3.y * xr[k + 1] + n3.z * xr[k + 2] + n3.w * xr[k + 3];
            }
            float4 rd  = *(const float4*)&rdiag[i0];
            float4 nb1 = *(const float4*)&Nrow[(i0 + 1) * ST + i0];
            float4 nb2 = *(const float4*)&Nrow[(i0 + 2) * ST + i0];
            float4 nb3 = *(const float4*)&Nrow[(i0 + 3) * ST + i0];
            float x0 = a0 * rd.x;
            float x1 = (a1 - nb1.x * x0) * rd.y;
            float x2 = (a2 - nb2.x * x0 - nb2.y * x1) * rd.z;
            float x3 = (a3 - nb3.x * x0 - nb3.y * x1 - nb3.z * x2) * rd.w;
            xr[i0 + 0] = x0; xr[i0 + 1] = x1; xr[i0 + 2] = x2; xr[i0 + 3] = x3;
        }
        float* xrow = &Mcol[tid * ST];
#pragma unroll
        for (int k = 0; k < NS; k += 4) {
            float4 v = {xr[k], xr[k + 1], xr[k + 2], xr[k + 3]};
            *(float4*)&xrow[k] = v;
        }
    }
    __syncthreads();

    // transpose Mcol -> Mrow; block 0 stores ABAR+BBAR; seed VT col 0
    if (tid < 256) {
        const int i0 = 4 * (tid >> 4), j0 = 4 * (tid & 15);
        float4 r0 = *(const float4*)&Mcol[(j0 + 0) * ST + i0];
        float4 r1 = *(const float4*)&Mcol[(j0 + 1) * ST + i0];
        float4 r2 = *(const float4*)&Mcol[(j0 + 2) * ST + i0];
        float4 r3 = *(const float4*)&Mcol[(j0 + 3) * ST + i0];
        float4 w0 = {r0.x, r1.x, r2.x, r3.x};
        float4 w1 = {r0.y, r1.y, r2.y, r3.y};
        float4 w2 = {r0.z, r1.z, r2.z, r3.z};
        float4 w3 = {r0.w, r1.w, r2.w, r3.w};
        *(float4*)&Mrow[(i0 + 0) * ST + j0] = w0;
        *(float4*)&Mrow[(i0 + 1) * ST + j0] = w1;
        *(float4*)&Mrow[(i0 + 2) * ST + j0] = w2;
        *(float4*)&Mrow[(i0 + 3) * ST + j0] = w3;
        if (b == 0) {
            *(float4*)&ws[WS_ABAR + (i0 + 0) * NS + j0] = w0;
            *(float4*)&ws[WS_ABAR + (i0 + 1) * NS + j0] = w1;
            *(float4*)&ws[WS_ABAR + (i0 + 2) * NS + j0] = w2;
            *(float4*)&ws[WS_ABAR + (i0 + 3) * NS + j0] = w3;
        }
    }
    if (b == 0 && tid < 16)
        *(float4*)&ws[WS_BBAR + 4 * tid] = *(const float4*)&Mcol[NS * ST + 4 * tid];
    if (tid < NS) VT[tid * ST + 0] = Mcol[NS * ST + tid];
    __syncthreads();

    // 6 levels: waves 0-3 square (A^m -> A^2m), waves 4-7 expand vs cols.
    float *cm = Mrow, *cmt = Mcol, *nm = Nrow, *nmt = Ncol;
    const int l = tid & 63;
    const int si0 = 16 * ((tid >> 6) & 3) + 4 * (l >> 4);
    const int sj0 = 4 * (l & 15);
    for (int s = 1; s <= 6; ++s) {
        if (tid < 256) {
            float4 a0 = {0,0,0,0}, a1 = {0,0,0,0}, a2 = {0,0,0,0}, a3 = {0,0,0,0};
#pragma unroll 4
            for (int k = 0; k < NS; k += 4) {
                float4 av0 = *(const float4*)&cmt[(k + 0) * ST + si0];
                float4 bv0 = *(const float4*)&cm [(k + 0) * ST + sj0];
                float4 av1 = *(const float4*)&cmt[(k + 1) * ST + si0];
                float4 bv1 = *(const float4*)&cm [(k + 1) * ST + sj0];
                float4 av2 = *(const float4*)&cmt[(k + 2) * ST + si0];
                float4 bv2 = *(const float4*)&cm [(k + 2) * ST + sj0];
                float4 av3 = *(const float4*)&cmt[(k + 3) * ST + si0];
                float4 bv3 = *(const float4*)&cm [(k + 3) * ST + sj0];
                FMA44(av0, bv0)
                FMA44(av1, bv1)
                FMA44(av2, bv2)
                FMA44(av3, bv3)
            }
            *(float4*)&nm[(si0 + 0) * ST + sj0] = a0;
            *(float4*)&nm[(si0 + 1) * ST + sj0] = a1;
            *(float4*)&nm[(si0 + 2) * ST + sj0] = a2;
            *(float4*)&nm[(si0 + 3) * ST + sj0] = a3;
            float4 t0 = {a0.x, a1.x, a2.x, a3.x};
            float4 t1 = {a0.y, a1.y, a2.y, a3.y};
            float4 t2 = {a0.z, a1.z, a2.z, a3.z};
            float4 t3 = {a0.w, a1.w, a2.w, a3.w};
            *(float4*)&nmt[(sj0 + 0) * ST + si0] = t0;
            *(float4*)&nmt[(sj0 + 1) * ST + si0] = t1;
            *(float4*)&nmt[(sj0 + 2) * ST + si0] = t2;
            *(float4*)&nmt[(sj0 + 3) * ST + si0] = t3;
        } else {
            const int e = tid - 256;
            if (s == 1) {
                if (e < NS) {   // col 1 = A * col 0
                    float sum = 0.f;
#pragma unroll 8
                    for (int k = 0; k < NS; ++k) sum += cmt[k * ST + e] * VT[k * ST + 0];
                    VT[e * ST + 1] = sum;
                }
            } else if (s == 2) {
                if (e < 2 * NS) {   // cols 2,3 = A^2 * cols 0,1
                    const int i = e & 63, j = e >> 6;
                    float sum = 0.f;
#pragma unroll 8
                    for (int k = 0; k < NS; ++k) sum += cmt[k * ST + i] * VT[k * ST + j];
                    VT[i * ST + 2 + j] = sum;
                }
            } else {
                const int mexp = 1 << (s - 1);   // 4,8,16,32
                if (e < 4 * mexp) {   // cols [mexp, 2*mexp) = A^mexp * cols [0, mexp)
                    const int vi = 4 * (e & 15), vj = 4 * (e >> 4);
                    float4 a0 = {0,0,0,0}, a1 = {0,0,0,0}, a2 = {0,0,0,0}, a3 = {0,0,0,0};
#pragma unroll 4
                    for (int k = 0; k < NS; k += 2) {
                        float4 av  = *(const float4*)&cmt[k * ST + vi];
                        float4 bv  = *(const float4*)&VT [k * ST + vj];
                        float4 av2 = *(const float4*)&cmt[(k + 1) * ST + vi];
                        float4 bv2 = *(const float4*)&VT [(k + 1) * ST + vj];
                        FMA44(av, bv)
                        FMA44(av2, bv2)
                    }
                    *(float4*)&VT[(vi + 0) * ST + vj + mexp] = a0;
                    *(float4*)&VT[(vi + 1) * ST + vj + mexp] = a1;
                    *(float4*)&VT[(vi + 2) * ST + vj + mexp] = a2;
                    *(float4*)&VT[(vi + 3) * ST + vj + mexp] = a3;
                }
            }
        }
        __syncthreads();
        { float* t = cm; cm = nm; nm = t; t = cmt; cmt = nmt; nmt = t; }
        if (s == 4 && b == 0) {   // cm == A^16
            for (int o = tid; o < (NS * NS) / 4; o += 512) {
                int r = o >> 4, c4 = (o & 15) * 4;
                *(float4*)&ws[WS_A16 + r * NS + c4] = *(const float4*)&cm[r * ST + c4];
            }
        }
    }
    // cm (== Mrow) = A^64; Nrow/Ncol dead.

    // VT -> vsS transpose; block 0 stores VS
    if (tid < 256) {
        const int i0 = 4 * (tid >> 4), j0 = 4 * (tid & 15);
        float4 v0 = *(const float4*)&VT[(i0 + 0) * ST + j0];
        float4 v1 = *(const float4*)&VT[(i0 + 1) * ST + j0];
        float4 v2 = *(const float4*)&VT[(i0 + 2) * ST + j0];
        float4 v3 = *(const float4*)&VT[(i0 + 3) * ST + j0];
        float4 w0 = {v0.x, v1.x, v2.x, v3.x};
        float4 w1 = {v0.y, v1.y, v2.y, v3.y};
        float4 w2 = {v0.z, v1.z, v2.z, v3.z};
        float4 w3 = {v0.w, v1.w, v2.w, v3.w};
        *(float4*)&vsS[(j0 + 0) * NS + i0] = w0;
        *(float4*)&vsS[(j0 + 1) * NS + i0] = w1;
        *(float4*)&vsS[(j0 + 2) * NS + i0] = w2;
        *(float4*)&vsS[(j0 + 3) * NS + i0] = w3;
        if (b == 0) {
            *(float4*)&ws[WS_VS + (j0 + 0) * NS + i0] = w0;
            *(float4*)&ws[WS_VS + (j0 + 1) * NS + i0] = w1;
            *(float4*)&ws[WS_VS + (j0 + 2) * NS + i0] = w2;
            *(float4*)&ws[WS_VS + (j0 + 3) * NS + i0] = w3;
        }
    }
    // stage u transposed into dead Nrow: uT[jj][m] = u[b][m*64 + 63-jj]
    {
        const int jj = tid & 63;
#pragma unroll
        for (int rep = 0; rep < 2; ++rep) {
            const int m0 = 4 * (tid >> 6) + 32 * rep;
            float4 v;
            v.x = u[b * LSEQ + (m0 + 0) * SCH + 63 - jj];
            v.y = u[b * LSEQ + (m0 + 1) * SCH + 63 - jj];
            v.z = u[b * LSEQ + (m0 + 2) * SCH + 63 - jj];
            v.w = u[b * LSEQ + (m0 + 3) * SCH + 63 - jj];
            *(float4*)&Nrow[jj * ST + m0] = v;
        }
    }
    const int i = tid & 63, q = (tid >> 6) & 3;
    float4 a64[4];
    if (tid < 256) {
#pragma unroll
        for (int kq = 0; kq < 4; ++kq)
            a64[kq] = *(const float4*)&Mrow[i * ST + 16 * q + 4 * kq];
    }
    if (tid < NS) xcS[tid] = 0.f;
    __syncthreads();

    // xle[m][i] = sum_j vs[j][i] * uT[j][m]
    if (tid < 256) {
        const int ig = tid & 15, mg = tid >> 4;
        float4 a0 = {0,0,0,0}, a1 = {0,0,0,0}, a2 = {0,0,0,0}, a3 = {0,0,0,0};
#pragma unroll 4
        for (int j = 0; j < NS; j += 2) {
            float4 am  = *(const float4*)&Nrow[j * ST + 4 * mg];
            float4 bi  = *(const float4*)&vsS[j * NS + 4 * ig];
            float4 am2 = *(const float4*)&Nrow[(j + 1) * ST + 4 * mg];
            float4 bi2 = *(const float4*)&vsS[(j + 1) * NS + 4 * ig];
            FMA44(am, bi)
            FMA44(am2, bi2)
        }
        *(float4*)&xleS[(4 * mg + 0) * NS + 4 * ig] = a0;
        *(float4*)&xleS[(4 * mg + 1) * NS + 4 * ig] = a1;
        *(float4*)&xleS[(4 * mg + 2) * NS + 4 * ig] = a2;
        *(float4*)&xleS[(4 * mg + 3) * NS + 4 * ig] = a3;
    }
    __syncthreads();

    // 64-step chunk scan (waves 0-3 work; all threads hit barriers)
    for (int m = 0; m < MCH; ++m) {
        if (tid < 256) {
            if (q == 0 && tid < 64) out[X0_IDX(b, m) + i] = xcS[i];
            float4 t0 = *(const float4*)(xcS + 16 * q + 0);
            float4 t1 = *(const float4*)(xcS + 16 * q + 4);
            float4 t2 = *(const float4*)(xcS + 16 * q + 8);
            float4 t3 = *(const float4*)(xcS + 16 * q + 12);
            float s = a64[0].x * t0.x + a64[0].y * t0.y + a64[0].z * t0.z + a64[0].w * t0.w
                    + a64[1].x * t1.x + a64[1].y * t1.y + a64[1].z * t1.z + a64[1].w * t1.w
                    + a64[2].x * t2.x + a64[2].y * t2.y + a64[2].z * t2.z + a64[2].w * t2.w
                    + a64[3].x * t3.x + a64[3].y * t3.y + a64[3].z * t3.z + a64[3].w * t3.w;
            part[m & 1][q * 64 + i] = s;
        }
        __syncthreads();
        if (tid < 256) {
            float xn = part[m & 1][i] + part[m & 1][64 + i] + part[m & 1][128 + i]
                     + part[m & 1][192 + i] + xleS[m * 64 + i];
            xcS[i] = xn;   // all 4 waves write identical bits
        }
    }
}

// ---------------------------------------------------------------------------
// K2: main. Phase 1 = A^16 mini-scan + per-wave paragraph recurrence (proven).
// Phase 2 = C@X on all 4 waves. Phase-1 scratch aliased into the C^T pool
// -> 51.2 KB LDS -> 3 blocks/CU.
// ---------------------------------------------------------------------------
__global__ __launch_bounds__(256) void k_main2(const float* __restrict__ u,
                                               const float* __restrict__ Cm,
                                               const float* __restrict__ Dv,
                                               const float* __restrict__ ws,
                                               float* __restrict__ out) {
    __shared__ __align__(16) float Xl[NS * ST];     // A_bar staging, then X[i][t]
    __shared__ __align__(16) float pool[NS * CP];   // phase1 scratch+A16, then C^T
    __shared__ float uS[SCH], DS[CH], bbS[NS];
    const int m = blockIdx.x, b = blockIdx.y;
    const int tid = threadIdx.x;
    const int l = tid & 63, w = tid >> 6;

    for (int o = tid; o < (NS * NS) / 4; o += 256) {
        int r = o >> 4, c4 = (o & 15) * 4;
        *(float4*)&Xl[r * ST + c4]          = *(const float4*)&ws[WS_ABAR + r * NS + c4];
        *(float4*)&pool[P_A16 + r * NS + c4] = *(const float4*)&ws[WS_A16 + r * NS + c4];
    }
    for (int o = tid; o < 16 * NS; o += 256) pool[P_VSS + o] = ws[WS_VS + o];
    if (tid < NS) {
        uS[tid]  = u[b * LSEQ + m * SCH + tid];
        bbS[tid] = ws[WS_BBAR + tid];
        pool[P_XBS + tid] = out[X0_IDX(b, m) + tid];
    }
    if (tid < CH) DS[tid] = Dv[tid];
    __syncthreads();

    const int r0 = l & 15, q = l >> 4;
    float4 ar[4][4];
#pragma unroll
    for (int b4 = 0; b4 < 4; ++b4)
#pragma unroll
        for (int kq = 0; kq < 4; ++kq)
            ar[b4][kq] = *(const float4*)&Xl[(r0 + 16 * b4) * ST + 16 * q + 4 * kq];
    float bbr[4];
#pragma unroll
    for (int b4 = 0; b4 < 4; ++b4) bbr[b4] = bbS[r0 + 16 * b4];
    float4 a16r[4];
#pragma unroll
    for (int kq = 0; kq < 4; ++kq)
        a16r[kq] = *(const float4*)&pool[P_A16 + l * NS + 16 * w + 4 * kq];

    {
        float s = 0.f;
#pragma unroll
        for (int j = 0; j < 16; ++j) s += pool[P_VSS + j * NS + l] * uS[16 * w + 15 - j];
        pool[P_PLE + w * NS + l] = s;
    }
    __syncthreads();

    for (int p = 1; p < 4; ++p) {
        float4 x0q = *(const float4*)&pool[P_XBS + (p - 1) * NS + 16 * w + 0];
        float4 x1q = *(const float4*)&pool[P_XBS + (p - 1) * NS + 16 * w + 4];
        float4 x2q = *(const float4*)&pool[P_XBS + (p - 1) * NS + 16 * w + 8];
        float4 x3q = *(const float4*)&pool[P_XBS + (p - 1) * NS + 16 * w + 12];
        float s = a16r[0].x * x0q.x + a16r[0].y * x0q.y + a16r[0].z * x0q.z + a16r[0].w * x0q.w
                + a16r[1].x * x1q.x + a16r[1].y * x1q.y + a16r[1].z * x1q.z + a16r[1].w * x1q.w
                + a16r[2].x * x2q.x + a16r[2].y * x2q.y + a16r[2].z * x2q.z + a16r[2].w * x2q.w
                + a16r[3].x * x3q.x + a16r[3].y * x3q.y + a16r[3].z * x3q.z + a16r[3].w * x3q.w;
        pool[P_PART + w * NS + l] = s;
        __syncthreads();
        if (w == 0) {
            float xn = pool[P_PART + l] + pool[P_PART + NS + l] + pool[P_PART + 2 * NS + l]
                     + pool[P_PART + 3 * NS + l] + pool[P_PLE + (p - 1) * NS + l];
            pool[P_XBS + p * NS + l] = xn;
        }
        __syncthreads();
    }

    pool[P_XCW + w * NS + l] = pool[P_XBS + w * NS + l];
    for (int s = 0; s < 16; ++s) {
        __threadfence_block();
        const int t = 16 * w + s;
        float4 x0q = *(const float4*)&pool[P_XCW + w * NS + 16 * q + 0];
        float4 x1q = *(const float4*)&pool[P_XCW + w * NS + 16 * q + 4];
        float4 x2q = *(const float4*)&pool[P_XCW + w * NS + 16 * q + 8];
        float4 x3q = *(const float4*)&pool[P_XCW + w * NS + 16 * q + 12];
        float p0, p1, p2, p3;
        p0 = ar[0][0].x * x0q.x + ar[0][0].y * x0q.y + ar[0][0].z * x0q.z + ar[0][0].w * x0q.w
           + ar[0][1].x * x1q.x + ar[0][1].y * x1q.y + ar[0][1].z * x1q.z + ar[0][1].w * x1q.w
           + ar[0][2].x * x2q.x + ar[0][2].y * x2q.y + ar[0][2].z * x2q.z + ar[0][2].w * x2q.w
           + ar[0][3].x * x3q.x + ar[0][3].y * x3q.y + ar[0][3].z * x3q.z + ar[0][3].w * x3q.w;
        p1 = ar[1][0].x * x0q.x + ar[1][0].y * x0q.y + ar[1][0].z * x0q.z + ar[1][0].w * x0q.w
           + ar[1][1].x * x1q.x + ar[1][1].y * x1q.y + ar[1][1].z * x1q.z + ar[1][1].w * x1q.w
           + ar[1][2].x * x2q.x + ar[1][2].y * x2q.y + ar[1][2].z * x2q.z + ar[1][2].w * x2q.w
           + ar[1][3].x * x3q.x + ar[1][3].y * x3q.y + ar[1][3].z * x3q.z + ar[1][3].w * x3q.w;
        p2 = ar[2][0].x * x0q.x + ar[2][0].y * x0q.y + ar[2][0].z * x0q.z + ar[2][0].w * x0q.w
           + ar[2][1].x * x1q.x + ar[2][1].y * x1q.y + ar[2][1].z * x1q.z + ar[2][1].w * x1q.w
           + ar[2][2].x * x2q.x + ar[2][2].y * x2q.y + ar[2][2].z * x2q.z + ar[2][2].w * x2q.w
           + ar[2][3].x * x3q.x + ar[2][3].y * x3q.y + ar[2][3].z * x3q.z + ar[2][3].w * x3q.w;
        p3 = ar[3][0].x * x0q.x + ar[3][0].y * x0q.y + ar[3][0].z * x0q.z + ar[3][0].w * x0q.w
           + ar[3][1].x * x1q.x + ar[3][1].y * x1q.y + ar[3][1].z * x1q.z + ar[3][1].w * x1q.w
           + ar[3][2].x * x2q.x + ar[3][2].y * x2q.y + ar[3][2].z * x2q.z + ar[3][2].w * x2q.w
           + ar[3][3].x * x3q.x + ar[3][3].y * x3q.y + ar[3][3].z * x3q.z + ar[3][3].w * x3q.w;
        p0 += __shfl_xor(p0, 16, 64); p1 += __shfl_xor(p1, 16, 64);
        p2 += __shfl_xor(p2, 16, 64); p3 += __shfl_xor(p3, 16, 64);
        p0 += __shfl_xor(p0, 32, 64); p1 += __shfl_xor(p1, 32, 64);
        p2 += __shfl_xor(p2, 32, 64); p3 += __shfl_xor(p3, 32, 64);
        const float ut = uS[t];
        p0 += bbr[0] * ut; p1 += bbr[1] * ut; p2 += bbr[2] * ut; p3 += bbr[3] * ut;
        const float xv = (q == 0) ? p0 : (q == 1) ? p1 : (q == 2) ? p2 : p3;
        const int row = r0 + 16 * q;
        pool[P_XCW + w * NS + row] = xv;
        Xl[row * ST + t] = xv;
    }
    __syncthreads();

    // phase2: stage C^T over the whole pool (stride 128)
#pragma unroll
    for (int rep = 0; rep < 8; ++rep) {
        const int ii = tid & 63;
        const int cg = (tid >> 6) + 4 * rep;   // 0..31
        float4 v;
        v.x = Cm[(4 * cg + 0) * NS + ii];
        v.y = Cm[(4 * cg + 1) * NS + ii];
        v.z = Cm[(4 * cg + 2) * NS + ii];
        v.w = Cm[(4 * cg + 3) * NS + ii];
        *(float4*)&pool[ii * CP + 4 * cg] = v;
    }
    __syncthreads();

    {
        const int tg = tid & 7, cq = tid >> 3;   // t0 = 8*tg, c0 = 4*cq
        float acc[4][8];
#pragma unroll
        for (int r = 0; r < 4; ++r)
#pragma unroll
            for (int c = 0; c < 8; ++c) acc[r][c] = 0.f;
#pragma unroll 4
        for (int ii = 0; ii < NS; ++ii) {
            float4 cv = *(const float4*)&pool[ii * CP + 4 * cq];
            float4 xa = *(const float4*)&Xl[ii * ST + 8 * tg + 0];
            float4 xb = *(const float4*)&Xl[ii * ST + 8 * tg + 4];
            float cr[4] = {cv.x, cv.y, cv.z, cv.w};
            float xv[8] = {xa.x, xa.y, xa.z, xa.w, xb.x, xb.y, xb.z, xb.w};
#pragma unroll
            for (int r = 0; r < 4; ++r)
#pragma unroll
                for (int c = 0; c < 8; ++c) acc[r][c] += cr[r] * xv[c];
        }
        const size_t obase = ((size_t)b * CH) * LSEQ + (size_t)m * SCH + 8 * tg;
#pragma unroll
        for (int r = 0; r < 4; ++r) {
            const int c = 4 * cq + r;
            const float dv = DS[c];
            float4 o1, o2;
            o1.x = acc[r][0] + dv * uS[8 * tg + 0];
            o1.y = acc[r][1] + dv * uS[8 * tg + 1];
            o1.z = acc[r][2] + dv * uS[8 * tg + 2];
            o1.w = acc[r][3] + dv * uS[8 * tg + 3];
            o2.x = acc[r][4] + dv * uS[8 * tg + 4];
            o2.y = acc[r][5] + dv * uS[8 * tg + 5];
            o2.z = acc[r][6] + dv * uS[8 * tg + 6];
            o2.w = acc[r][7] + dv * uS[8 * tg + 7];
            float* op = out + obase + (size_t)c * LSEQ;
            *(float4*)(op)     = o1;
            *(float4*)(op + 4) = o2;
        }
    }
}

extern "C" void kernel_launch(void* const* d_in, const int* in_sizes, int n_in,
                              void* d_out, int out_size, void* d_ws, size_t ws_size,
                              hipStream_t stream) {
    const float* u   = (const float*)d_in[0];
    const float* A   = (const float*)d_in[1];
    const float* Bv  = (const float*)d_in[2];
    const float* Cm  = (const float*)d_in[3];
    const float* Dv  = (const float*)d_in[4];
    const float* dtp = (const float*)d_in[5];
    float* ws  = (float*)d_ws;
    float* out = (float*)d_out;

    k_sb<<<NB, 512, 0, stream>>>(u, A, Bv, dtp, ws, out);
    k_main2<<<dim3(MCH, NB), 256, 0, stream>>>(u, Cm, Dv, ws, out);
}